// Round 6
// baseline (871.591 us; speedup 1.0000x reference)
//
#include <hip/hip_runtime.h>

#define GG 256

typedef __bf16 bf16x8 __attribute__((ext_vector_type(8)));
typedef float floatx4 __attribute__((ext_vector_type(4)));
typedef float f32x2 __attribute__((ext_vector_type(2)));

__device__ __forceinline__ float lrelu(float x) { return x > 0.f ? x : 0.2f * x; }

// e_bf[n,c] = bf16(emb[xi[n]*128 + c]); 16 threads/node, 8 ch each
__global__ void k_embed_bf(const int* __restrict__ xi, const float* __restrict__ emb,
                           __bf16* __restrict__ e, int n) {
    int t = blockIdx.x * blockDim.x + threadIdx.x;
    if (t >= n * 16) return;
    int node = t >> 4, c0 = (t & 15) * 8;
    const float4* src = (const float4*)(emb + ((size_t)xi[node] << 7) + c0);
    float4 v0 = src[0], v1 = src[1];
    bf16x8 o = {(__bf16)v0.x, (__bf16)v0.y, (__bf16)v0.z, (__bf16)v0.w,
                (__bf16)v1.x, (__bf16)v1.y, (__bf16)v1.z, (__bf16)v1.w};
    *(bf16x8*)(e + (size_t)node * 128 + c0) = o;
}

// Bt[m*K+k] = bf16(B[k*M+m])
__global__ void k_wt(const float* __restrict__ B, __bf16* __restrict__ Bt, int K, int M) {
    int idx = blockIdx.x * blockDim.x + threadIdx.x;
    if (idx >= K * M) return;
    int k = idx / M, m = idx - k * M;
    Bt[(size_t)m * K + k] = (__bf16)B[idx];
}

// attn proj rows: dst[j*K+k] = j<4: sum_c W[k, j*C+c]*att_s[j*C+c]
//                              j in 4..8: same with att_d; j in 8..16: 0
__global__ void k_wattn(const float* __restrict__ W, const float* __restrict__ att_s,
                        const float* __restrict__ att_d, __bf16* __restrict__ dst,
                        int K, int C) {
    int idx = blockIdx.x * blockDim.x + threadIdx.x;
    if (idx >= 16 * K) return;
    int j = idx / K, k = idx - j * K;
    float v = 0.f;
    if (j < 8) {
        int h = j & 3;
        const float* att = (j < 4) ? att_s : att_d;
        int M = 4 * C;
        for (int c = 0; c < C; c++) v += W[(size_t)k * M + h * C + c] * att[h * C + c];
    }
    dst[(size_t)j * K + k] = (__bf16)v;
}

// All-in-one GEMM: A[n,K] @ Bt[Mtot+16,K]^T. Stages full-K A tile (64 rows) in
// LDS once, hoists A-frags to registers, loops over its half of the col tiles
// reading B from global (L2-resident). cols<Mx -> xh bf16; [Mx,Mtot) -> lin
// fp32 +bias1(+bias2); mini-tile [Mtot,Mtot+16) -> a_s/a_d (cy==1 only).
template <int K>
__global__ __launch_bounds__(256) void k_gemm_all(const __bf16* __restrict__ A,
                                                  const __bf16* __restrict__ Bt,
                                                  int n, int Mx, int Ml,
                                                  __bf16* __restrict__ xh, int ldx,
                                                  float* __restrict__ lin, int ldl,
                                                  const float* __restrict__ bias1,
                                                  const float* __restrict__ bias2,
                                                  float* __restrict__ a_s,
                                                  float* __restrict__ a_d) {
    constexpr int KS = K / 32;
    __shared__ __bf16 As[64][K + 8];
    int tid = threadIdx.x;
    int wave = tid >> 6, lane = tid & 63;
    int row0 = blockIdx.x * 64;
    constexpr int LPR = K / 8;  // bf16x8 loads per row
    for (int i = tid; i < 64 * LPR; i += 256) {
        int r = i / LPR, ko = (i - r * LPR) * 8;
        int gr = row0 + r;
        bf16x8 v = {};
        if (gr < n) v = *(const bf16x8*)(A + (size_t)gr * K + ko);
        *(bf16x8*)&As[r][ko] = v;
    }
    __syncthreads();
    int kOff = (lane >> 4) * 8;
    bf16x8 af[KS];
#pragma unroll
    for (int ks = 0; ks < KS; ks++)
        af[ks] = *(const bf16x8*)&As[wave * 16 + (lane & 15)][ks * 32 + kOff];
    int Mtot = Mx + Ml;
    int colBase = lane & 15;
    int gr0 = row0 + wave * 16 + ((lane >> 4) << 2);
    int half = (Mtot / 128) * 64;           // tiles split evenly (Mtot/64 is even)
    int c0beg = blockIdx.y * half;
    int c0end = c0beg + half;
    for (int c0 = c0beg; c0 < c0end; c0 += 64) {
        floatx4 acc[4] = {};
#pragma unroll
        for (int ct = 0; ct < 4; ct++) {
            const __bf16* bp = Bt + (size_t)(c0 + ct * 16 + colBase) * K + kOff;
#pragma unroll
            for (int ks = 0; ks < KS; ks++) {
                bf16x8 bf = *(const bf16x8*)(bp + ks * 32);
                acc[ct] = __builtin_amdgcn_mfma_f32_16x16x32_bf16(af[ks], bf, acc[ct], 0, 0, 0);
            }
        }
        if (c0 < Mx) {
#pragma unroll
            for (int r = 0; r < 4; r++) {
                int gr = gr0 + r;
                if (gr >= n) continue;
#pragma unroll
                for (int ct = 0; ct < 4; ct++)
                    xh[(size_t)gr * ldx + c0 + ct * 16 + colBase] = (__bf16)acc[ct][r];
            }
        } else {
#pragma unroll
            for (int r = 0; r < 4; r++) {
                int gr = gr0 + r;
                if (gr >= n) continue;
#pragma unroll
                for (int ct = 0; ct < 4; ct++) {
                    int c2 = c0 + ct * 16 + colBase - Mx;
                    float v = acc[ct][r] + bias1[c2];
                    if (bias2) v += bias2[c2];
                    lin[(size_t)gr * ldl + c2] = v;
                }
            }
        }
    }
    if (blockIdx.y == 1) {  // attn mini-tile (16 cols: 4 a_s, 4 a_d, 8 zero)
        floatx4 acc = {};
        const __bf16* bp = Bt + (size_t)(Mtot + colBase) * K + kOff;
#pragma unroll
        for (int ks = 0; ks < KS; ks++) {
            bf16x8 bf = *(const bf16x8*)(bp + ks * 32);
            acc = __builtin_amdgcn_mfma_f32_16x16x32_bf16(af[ks], bf, acc, 0, 0, 0);
        }
        if (colBase < 8) {
            float* dst = (colBase < 4) ? a_s : a_d;
            int h = colBase & 3;
#pragma unroll
            for (int r = 0; r < 4; r++) {
                int gr = gr0 + r;
                if (gr < n) dst[gr * 4 + h] = acc[r];
            }
        }
    }
}

// ---- CSR build ----
__global__ void k_hist(const int* __restrict__ edges, int E, int* __restrict__ deg) {
    int e = blockIdx.x * blockDim.x + threadIdx.x;
    if (e < E) atomicAdd(&deg[edges[E + e]], 1);
}

__global__ __launch_bounds__(1024) void k_scan(int* __restrict__ rp, int n) {
    __shared__ int wsum[16];
    __shared__ int s_carry;
    int lane = threadIdx.x & 63, wid = threadIdx.x >> 6;
    if (threadIdx.x == 0) s_carry = 0;
    __syncthreads();
    for (int base = 0; base < n; base += 1024) {
        int i = base + threadIdx.x;
        int v = (i < n) ? rp[i] : 0;
        int inc = v;
#pragma unroll
        for (int off = 1; off < 64; off <<= 1) {
            int t = __shfl_up(inc, off, 64);
            if (lane >= off) inc += t;
        }
        if (lane == 63) wsum[wid] = inc;
        __syncthreads();
        int carry = s_carry;
        __syncthreads();
        if (wid == 0) {
            int wv = (lane < 16) ? wsum[lane] : 0;
            int winc = wv;
#pragma unroll
            for (int off = 1; off < 16; off <<= 1) {
                int t = __shfl_up(winc, off, 64);
                if (lane >= off) winc += t;
            }
            if (lane < 16) wsum[lane] = winc - wv;
            if (lane == 15) s_carry = carry + winc;
        }
        __syncthreads();
        if (i < n) rp[i] = carry + wsum[wid] + (inc - v);
        __syncthreads();
    }
}

__global__ void k_fill(const int* __restrict__ edges, int E, int* __restrict__ rp,
                       int* __restrict__ csr) {
    int e = blockIdx.x * blockDim.x + threadIdx.x;
    if (e >= E) return;
    int d = edges[E + e];
    int pos = atomicAdd(&rp[d], 1);
    csr[pos] = edges[e];
}

// graph boundaries from sorted batch
__global__ void k_gbound(const int* __restrict__ batch, int n, int* __restrict__ gs) {
    int g = blockIdx.x * blockDim.x + threadIdx.x;
    if (g > GG) return;
    int lo = 0, hi = n;
    while (lo < hi) {
        int mid = (lo + hi) >> 1;
        if (batch[mid] < g) lo = mid + 1; else hi = mid;
    }
    gs[g] = lo;
}

// Layers 1/2 aggregation: 2 nodes/wave (32 lanes x 8 bf16 ch each), no max pass.
__global__ __launch_bounds__(256) void k_agg12(const int* __restrict__ rp,
                                               const int* __restrict__ csr,
                                               const float* __restrict__ a_s,
                                               const float* __restrict__ a_d,
                                               const __bf16* __restrict__ xh,
                                               const float* __restrict__ lin,
                                               __bf16* __restrict__ out_bf, int n) {
    int wv = (int)((blockIdx.x * blockDim.x + threadIdx.x) >> 6);
    int lane = threadIdx.x & 63;
    int sub = lane >> 5, sl = lane & 31;
    int node = wv * 2 + sub;
    if (node >= n) return;
    int sbase = lane & 32;
    int c0 = sl * 8;
    int h = sl >> 3;
    int start = node ? rp[node - 1] : 0;
    int end = rp[node];
    float ad = a_d[node * 4 + h];
    float z = __expf(lrelu(a_s[node * 4 + h] + ad));
    float acc[8];
    {
        bf16x8 v = *(const bf16x8*)(xh + (size_t)node * 256 + c0);
#pragma unroll
        for (int j = 0; j < 8; j++) acc[j] = z * (float)v[j];
    }
    for (int eb = start; eb < end; eb += 32) {
        int myE = eb + sl;
        int mySrc = (myE < end) ? csr[myE] : 0;
        int cnt = min(32, end - eb);
        for (int j = 0; j < cnt; j++) {
            int s = __shfl(mySrc, sbase + j, 64);
            float w = __expf(lrelu(a_s[s * 4 + h] + ad));
            z += w;
            bf16x8 v = *(const bf16x8*)(xh + (size_t)s * 256 + c0);
#pragma unroll
            for (int q = 0; q < 8; q++) acc[q] += w * (float)v[q];
        }
    }
    float inv = 1.f / (z + 1e-16f);
    const float4* lp = (const float4*)(lin + (size_t)node * 256 + c0);
    float4 l0 = lp[0], l1 = lp[1];
    float lf[8] = {l0.x, l0.y, l0.z, l0.w, l1.x, l1.y, l1.z, l1.w};
    bf16x8 r;
#pragma unroll
    for (int j = 0; j < 8; j++)
        r[j] = (__bf16)fmaxf(acc[j] * inv + lf[j], 0.f);
    *(bf16x8*)(out_bf + (size_t)node * 256 + c0) = r;
}

// bf16 -> fp8 e4m3 (HW cvt), 8 elems/thread
__global__ void k_cvt8(const __bf16* __restrict__ src, unsigned int* __restrict__ dst,
                       int total8) {
    int t = blockIdx.x * blockDim.x + threadIdx.x;
    if (t >= total8) return;
    bf16x8 v = *(const bf16x8*)(src + (size_t)t * 8);
    int p0 = __builtin_amdgcn_cvt_pk_fp8_f32((float)v[0], (float)v[1], 0, false);
    p0 = __builtin_amdgcn_cvt_pk_fp8_f32((float)v[2], (float)v[3], p0, true);
    int p1 = __builtin_amdgcn_cvt_pk_fp8_f32((float)v[4], (float)v[5], 0, false);
    p1 = __builtin_amdgcn_cvt_pk_fp8_f32((float)v[6], (float)v[7], p1, true);
    ((uint2*)dst)[t] = make_uint2((unsigned int)p0, (unsigned int)p1);
}

__device__ __forceinline__ void dec4(unsigned int u, float* f) {
    f32x2 a = __builtin_amdgcn_cvt_pk_f32_fp8(u, false);
    f32x2 b = __builtin_amdgcn_cvt_pk_f32_fp8(u, true);
    f[0] = a[0]; f[1] = a[1]; f[2] = b[0]; f[3] = b[1];
}

// Layer-3 aggregation (HC=512) on fp8 rows; fused head-mean -> mean[n,128]
__global__ __launch_bounds__(256) void k_agg3(const int* __restrict__ rp,
                                              const int* __restrict__ csr,
                                              const float* __restrict__ a_s,
                                              const float* __restrict__ a_d,
                                              const unsigned int* __restrict__ x8,
                                              float* __restrict__ mean, int n) {
    int wv = (int)((blockIdx.x * blockDim.x + threadIdx.x) >> 6);
    int lane = threadIdx.x & 63;
    int sub = lane >> 5, sl = lane & 31;
    int node = wv * 2 + sub;
    if (node >= n) return;
    int sbase = lane & 32;
    int h = sl >> 3;
    int start = node ? rp[node - 1] : 0;
    int end = rp[node];
    float ad = a_d[node * 4 + h];
    float z = __expf(lrelu(a_s[node * 4 + h] + ad));
    float acc[16];
    {
        uint4 u = *(const uint4*)(x8 + (size_t)node * 128 + sl * 4);
        float f[16];
        dec4(u.x, f); dec4(u.y, f + 4); dec4(u.z, f + 8); dec4(u.w, f + 12);
#pragma unroll
        for (int j = 0; j < 16; j++) acc[j] = z * f[j];
    }
    for (int eb = start; eb < end; eb += 32) {
        int myE = eb + sl;
        int mySrc = (myE < end) ? csr[myE] : 0;
        int cnt = min(32, end - eb);
        for (int j = 0; j < cnt; j++) {
            int s = __shfl(mySrc, sbase + j, 64);
            float w = __expf(lrelu(a_s[s * 4 + h] + ad));
            z += w;
            uint4 u = *(const uint4*)(x8 + (size_t)s * 128 + sl * 4);
            float f[16];
            dec4(u.x, f); dec4(u.y, f + 4); dec4(u.z, f + 8); dec4(u.w, f + 12);
#pragma unroll
            for (int q = 0; q < 16; q++) acc[q] += w * f[q];
        }
    }
    float scale = 0.25f / (z + 1e-16f);
#pragma unroll
    for (int j = 0; j < 16; j++) {
        float v = acc[j] * scale;
        v += __shfl_xor(v, 8, 64);
        v += __shfl_xor(v, 16, 64);
        acc[j] = v;
    }
    if ((sl & 24) == 0) {
        float4* op = (float4*)(mean + (size_t)node * 128 + sl * 16);
#pragma unroll
        for (int q = 0; q < 4; q++) {
            float4 o = {acc[4 * q], acc[4 * q + 1], acc[4 * q + 2], acc[4 * q + 3]};
            op[q] = o;
        }
    }
}

// per-graph mean pool (no atomics)
__global__ __launch_bounds__(128) void k_pool(const float* __restrict__ mean,
                                              const float* __restrict__ lin3,
                                              const float* __restrict__ b3,
                                              const int* __restrict__ gs,
                                              float* __restrict__ out) {
    int g = blockIdx.x, c = threadIdx.x;
    int s = gs[g], e = gs[g + 1];
    float acc = 0.f;
    for (int i = s; i < e; i++)
        acc += mean[(size_t)i * 128 + c] + lin3[(size_t)i * 128 + c];
    int cnt = e - s;
    out[(size_t)g * 128 + c] = cnt > 0 ? acc / (float)cnt + b3[c] : 0.f;
}

static inline int cdiv(int a, int b) { return (a + b - 1) / b; }

extern "C" void kernel_launch(void* const* d_in, const int* in_sizes, int n_in,
                              void* d_out, int out_size, void* d_ws, size_t ws_size,
                              hipStream_t stream) {
    const int* x_l = (const int*)d_in[0];
    const int* edge_l = (const int*)d_in[1];
    const int* batch_l = (const int*)d_in[2];
    const int* x_r = (const int*)d_in[3];
    const int* edge_r = (const int*)d_in[4];
    const int* batch_r = (const int*)d_in[5];
    const float* emb = (const float*)d_in[6];
    const float* W1 = (const float*)d_in[7];
    const float* as1 = (const float*)d_in[8];
    const float* ad1 = (const float*)d_in[9];
    const float* b1 = (const float*)d_in[10];
    const float* lw1 = (const float*)d_in[11];
    const float* lb1 = (const float*)d_in[12];
    const float* W2 = (const float*)d_in[13];
    const float* as2 = (const float*)d_in[14];
    const float* ad2 = (const float*)d_in[15];
    const float* b2 = (const float*)d_in[16];
    const float* lw2 = (const float*)d_in[17];
    const float* lb2 = (const float*)d_in[18];
    const float* W3 = (const float*)d_in[19];
    const float* as3 = (const float*)d_in[20];
    const float* ad3 = (const float*)d_in[21];
    const float* b3 = (const float*)d_in[22];
    const float* lw3 = (const float*)d_in[23];
    const float* lb3 = (const float*)d_in[24];

    const int n = in_sizes[0];       // 20000
    const int E = in_sizes[1] / 2;   // 320000

    float* MEAN = (float*)d_ws;                // [n,128]
    float* LIN = MEAN + (size_t)n * 128;       // [n,256]
    float* L3 = LIN + (size_t)n * 256;         // [n,128]
    float* a_s = L3 + (size_t)n * 128;         // [n,4]
    float* a_d = a_s + (size_t)n * 4;
    int* rp = (int*)(a_d + (size_t)n * 4);     // [n]
    int* csr = rp + n;                         // [E]
    int* gs = csr + E;                         // [G+1]
    __bf16* Xbf = (__bf16*)(gs + GG + 1);      // [n,512]
    __bf16* Abf = Xbf + (size_t)n * 512;       // [n,256]
    unsigned int* X8 = (unsigned int*)(Abf + (size_t)n * 256);  // [n,128] fp8
    // combined transposed weights: [W^T | lw^T | attn(16 rows)]
    __bf16* B1t = (__bf16*)(X8 + (size_t)n * 128);   // 528 x 128
    __bf16* B2t = B1t + 528 * 128;                   // 528 x 256
    __bf16* B3t = B2t + 528 * 256;                   // 656 x 256

    const int TB = 256;
    dim3 blk(TB);

    // weight prep (shared by both sides)
    k_wt<<<cdiv(128 * 256, TB), blk, 0, stream>>>(W1, B1t, 128, 256);
    k_wt<<<cdiv(128 * 256, TB), blk, 0, stream>>>(lw1, B1t + 256 * 128, 128, 256);
    k_wattn<<<cdiv(16 * 128, TB), blk, 0, stream>>>(W1, as1, ad1, B1t + 512 * 128, 128, 64);
    k_wt<<<cdiv(256 * 256, TB), blk, 0, stream>>>(W2, B2t, 256, 256);
    k_wt<<<cdiv(256 * 256, TB), blk, 0, stream>>>(lw2, B2t + 256 * 256, 256, 256);
    k_wattn<<<cdiv(16 * 256, TB), blk, 0, stream>>>(W2, as2, ad2, B2t + 512 * 256, 256, 64);
    k_wt<<<cdiv(256 * 512, TB), blk, 0, stream>>>(W3, B3t, 256, 512);
    k_wt<<<cdiv(256 * 128, TB), blk, 0, stream>>>(lw3, B3t + 512 * 256, 256, 128);
    k_wattn<<<cdiv(16 * 256, TB), blk, 0, stream>>>(W3, as3, ad3, B3t + 640 * 256, 256, 128);

    for (int side = 0; side < 2; side++) {
        const int* xi = side ? x_r : x_l;
        const int* edges = side ? edge_r : edge_l;
        const int* batch = side ? batch_r : batch_l;
        float* pool = (float*)d_out + (size_t)side * GG * 128;

        // CSR + graph bounds
        hipMemsetAsync(rp, 0, sizeof(int) * (size_t)n, stream);
        k_hist<<<cdiv(E, TB), blk, 0, stream>>>(edges, E, rp);
        k_scan<<<1, 1024, 0, stream>>>(rp, n);
        k_fill<<<cdiv(E, TB), blk, 0, stream>>>(edges, E, rp, csr);
        k_gbound<<<1, 512, 0, stream>>>(batch, n, gs);

        // embed -> Abf [n,128]
        k_embed_bf<<<cdiv(n * 16, TB), blk, 0, stream>>>(xi, emb, Abf, n);

        // ---- layer 1 (K=128, Mx=256, Ml=256) ----
        k_gemm_all<128><<<dim3(cdiv(n, 64), 2), blk, 0, stream>>>(
            Abf, B1t, n, 256, 256, Xbf, 256, LIN, 256, lb1, b1, a_s, a_d);
        k_agg12<<<cdiv(n, 8), blk, 0, stream>>>(rp, csr, a_s, a_d, Xbf, LIN, Abf, n);

        // ---- layer 2 (K=256, Mx=256, Ml=256) ----
        k_gemm_all<256><<<dim3(cdiv(n, 64), 2), blk, 0, stream>>>(
            Abf, B2t, n, 256, 256, Xbf, 256, LIN, 256, lb2, b2, a_s, a_d);
        k_agg12<<<cdiv(n, 8), blk, 0, stream>>>(rp, csr, a_s, a_d, Xbf, LIN, Abf, n);

        // ---- layer 3 (K=256, Mx=512, Ml=128) ----
        k_gemm_all<256><<<dim3(cdiv(n, 64), 2), blk, 0, stream>>>(
            Abf, B3t, n, 512, 128, Xbf, 512, L3, 128, lb3, nullptr, a_s, a_d);
        k_cvt8<<<cdiv(n * 64, TB), blk, 0, stream>>>(Xbf, X8, n * 64);
        k_agg3<<<cdiv(n, 8), blk, 0, stream>>>(rp, csr, a_s, a_d, X8, MEAN, n);
        k_pool<<<GG, 128, 0, stream>>>(MEAN, L3, b3, gs, pool);
    }
}

// Round 7
// 713.342 us; speedup vs baseline: 1.2218x; 1.2218x over previous
//
#include <hip/hip_runtime.h>

#define GG 256

typedef __bf16 bf16x8 __attribute__((ext_vector_type(8)));
typedef float floatx4 __attribute__((ext_vector_type(4)));
typedef float f32x2 __attribute__((ext_vector_type(2)));

__device__ __forceinline__ float lrelu(float x) { return x > 0.f ? x : 0.2f * x; }

// e_bf[n,c] = bf16(emb[xi[n]*128 + c]); 16 threads/node, 8 ch each
__global__ void k_embed_bf(const int* __restrict__ xi, const float* __restrict__ emb,
                           __bf16* __restrict__ e, int n) {
    int t = blockIdx.x * blockDim.x + threadIdx.x;
    if (t >= n * 16) return;
    int node = t >> 4, c0 = (t & 15) * 8;
    const float4* src = (const float4*)(emb + ((size_t)xi[node] << 7) + c0);
    float4 v0 = src[0], v1 = src[1];
    bf16x8 o = {(__bf16)v0.x, (__bf16)v0.y, (__bf16)v0.z, (__bf16)v0.w,
                (__bf16)v1.x, (__bf16)v1.y, (__bf16)v1.z, (__bf16)v1.w};
    *(bf16x8*)(e + (size_t)node * 128 + c0) = o;
}

// Bt[m*K+k] = bf16(B[k*M+m])
__global__ void k_wt(const float* __restrict__ B, __bf16* __restrict__ Bt, int K, int M) {
    int idx = blockIdx.x * blockDim.x + threadIdx.x;
    if (idx >= K * M) return;
    int k = idx / M, m = idx - k * M;
    Bt[(size_t)m * K + k] = (__bf16)B[idx];
}

// attn proj rows: dst[j*K+k] = j<4: sum_c W[k,j*C+c]*att_s[h*C+c]; j 4..8: att_d; 8..16: 0
__global__ void k_wattn(const float* __restrict__ W, const float* __restrict__ att_s,
                        const float* __restrict__ att_d, __bf16* __restrict__ dst,
                        int K, int C) {
    int idx = blockIdx.x * blockDim.x + threadIdx.x;
    if (idx >= 16 * K) return;
    int j = idx / K, k = idx - j * K;
    float v = 0.f;
    if (j < 8) {
        int h = j & 3;
        const float* att = (j < 4) ? att_s : att_d;
        int M = 4 * C;
        for (int c = 0; c < C; c++) v += W[(size_t)k * M + h * C + c] * att[h * C + c];
    }
    dst[(size_t)j * K + k] = (__bf16)v;
}

// All-in-one GEMM: stage full-K A tile (64 rows) in LDS -> hoist A frags to
// registers -> REUSE the same LDS to stage each 64-col B tile (coalesced) ->
// MFMA with B frags from LDS. cols<Mx -> xh bf16; [Mx,Mtot) -> lin fp32
// +bias1(+bias2); mini-tile [Mtot,Mtot+16) -> a_s/a_d (blockIdx.y==1 only).
template <int K>
__global__ __launch_bounds__(256) void k_gemm_all(const __bf16* __restrict__ A,
                                                  const __bf16* __restrict__ Bt,
                                                  int n, int Mx, int Ml,
                                                  __bf16* __restrict__ xh, int ldx,
                                                  float* __restrict__ lin, int ldl,
                                                  const float* __restrict__ bias1,
                                                  const float* __restrict__ bias2,
                                                  float* __restrict__ a_s,
                                                  float* __restrict__ a_d) {
    constexpr int KS = K / 32;
    constexpr int LDK = K + 8;      // row stride: keeps 16B alignment, spreads banks
    constexpr int LPR = K / 8;      // bf16x8 chunks per row
    __shared__ __bf16 S[64 * LDK];  // A staging, then per-tile B staging
    int tid = threadIdx.x;
    int wave = tid >> 6, lane = tid & 63;
    int row0 = blockIdx.x * 64;
    // --- stage A (coalesced) ---
    for (int i = tid; i < 64 * LPR; i += 256) {
        int r = i / LPR, ko = (i - r * LPR) * 8;
        int gr = row0 + r;
        bf16x8 v = {};
        if (gr < n) v = *(const bf16x8*)(A + (size_t)gr * K + ko);
        *(bf16x8*)&S[r * LDK + ko] = v;
    }
    __syncthreads();
    int kOff = (lane >> 4) * 8;
    int colBase = lane & 15;
    // --- hoist A frags: wave owns rows [wave*16, wave*16+16) ---
    bf16x8 af[KS];
#pragma unroll
    for (int ks = 0; ks < KS; ks++)
        af[ks] = *(const bf16x8*)&S[(wave * 16 + colBase) * LDK + ks * 32 + kOff];
    __syncthreads();  // done reading A from LDS; safe to overwrite with B
    int Mtot = Mx + Ml;
    int gr0 = row0 + wave * 16 + ((lane >> 4) << 2);
    int half = (Mtot / 128) * 64;   // even split of col tiles across blockIdx.y
    int c0beg = blockIdx.y * half;
    int c0end = c0beg + half;
    for (int c0 = c0beg; c0 < c0end; c0 += 64) {
        // --- stage B tile rows [c0, c0+64) (coalesced) ---
        for (int i = tid; i < 64 * LPR; i += 256) {
            int r = i / LPR, ko = (i - r * LPR) * 8;
            *(bf16x8*)&S[r * LDK + ko] = *(const bf16x8*)(Bt + (size_t)(c0 + r) * K + ko);
        }
        __syncthreads();
        floatx4 acc[4] = {};
#pragma unroll
        for (int ct = 0; ct < 4; ct++) {
#pragma unroll
            for (int ks = 0; ks < KS; ks++) {
                bf16x8 bf = *(const bf16x8*)&S[(ct * 16 + colBase) * LDK + ks * 32 + kOff];
                acc[ct] = __builtin_amdgcn_mfma_f32_16x16x32_bf16(af[ks], bf, acc[ct], 0, 0, 0);
            }
        }
        __syncthreads();  // all waves done with this B tile before next overwrite
        // --- epilogue for this tile (registers only -> safe after sync) ---
        if (c0 < Mx) {
#pragma unroll
            for (int r = 0; r < 4; r++) {
                int gr = gr0 + r;
                if (gr >= n) continue;
#pragma unroll
                for (int ct = 0; ct < 4; ct++)
                    xh[(size_t)gr * ldx + c0 + ct * 16 + colBase] = (__bf16)acc[ct][r];
            }
        } else {
#pragma unroll
            for (int r = 0; r < 4; r++) {
                int gr = gr0 + r;
                if (gr >= n) continue;
#pragma unroll
                for (int ct = 0; ct < 4; ct++) {
                    int c2 = c0 + ct * 16 + colBase - Mx;
                    float v = acc[ct][r] + bias1[c2];
                    if (bias2) v += bias2[c2];
                    lin[(size_t)gr * ldl + c2] = v;
                }
            }
        }
    }
    if (blockIdx.y == 1) {  // attn mini-tile (16 cols: 4 a_s, 4 a_d, 8 zero) — tiny, L2-hot
        floatx4 acc = {};
        const __bf16* bp = Bt + (size_t)(Mtot + colBase) * K + kOff;
#pragma unroll
        for (int ks = 0; ks < KS; ks++) {
            bf16x8 bf = *(const bf16x8*)(bp + ks * 32);
            acc = __builtin_amdgcn_mfma_f32_16x16x32_bf16(af[ks], bf, acc, 0, 0, 0);
        }
        if (colBase < 8) {
            float* dst = (colBase < 4) ? a_s : a_d;
            int h = colBase & 3;
#pragma unroll
            for (int r = 0; r < 4; r++) {
                int gr = gr0 + r;
                if (gr < n) dst[gr * 4 + h] = acc[r];
            }
        }
    }
}

// ---- CSR build ----
__global__ void k_hist(const int* __restrict__ edges, int E, int* __restrict__ deg) {
    int e = blockIdx.x * blockDim.x + threadIdx.x;
    if (e < E) atomicAdd(&deg[edges[E + e]], 1);
}

__global__ __launch_bounds__(1024) void k_scan(int* __restrict__ rp, int n) {
    __shared__ int wsum[16];
    __shared__ int s_carry;
    int lane = threadIdx.x & 63, wid = threadIdx.x >> 6;
    if (threadIdx.x == 0) s_carry = 0;
    __syncthreads();
    for (int base = 0; base < n; base += 1024) {
        int i = base + threadIdx.x;
        int v = (i < n) ? rp[i] : 0;
        int inc = v;
#pragma unroll
        for (int off = 1; off < 64; off <<= 1) {
            int t = __shfl_up(inc, off, 64);
            if (lane >= off) inc += t;
        }
        if (lane == 63) wsum[wid] = inc;
        __syncthreads();
        int carry = s_carry;
        __syncthreads();
        if (wid == 0) {
            int wv = (lane < 16) ? wsum[lane] : 0;
            int winc = wv;
#pragma unroll
            for (int off = 1; off < 16; off <<= 1) {
                int t = __shfl_up(winc, off, 64);
                if (lane >= off) winc += t;
            }
            if (lane < 16) wsum[lane] = winc - wv;
            if (lane == 15) s_carry = carry + winc;
        }
        __syncthreads();
        if (i < n) rp[i] = carry + wsum[wid] + (inc - v);
        __syncthreads();
    }
}

__global__ void k_fill(const int* __restrict__ edges, int E, int* __restrict__ rp,
                       int* __restrict__ csr) {
    int e = blockIdx.x * blockDim.x + threadIdx.x;
    if (e >= E) return;
    int d = edges[E + e];
    int pos = atomicAdd(&rp[d], 1);
    csr[pos] = edges[e];
}

// graph boundaries from sorted batch
__global__ void k_gbound(const int* __restrict__ batch, int n, int* __restrict__ gs) {
    int g = blockIdx.x * blockDim.x + threadIdx.x;
    if (g > GG) return;
    int lo = 0, hi = n;
    while (lo < hi) {
        int mid = (lo + hi) >> 1;
        if (batch[mid] < g) lo = mid + 1; else hi = mid;
    }
    gs[g] = lo;
}

// Layers 1/2 aggregation: 2 nodes/wave (32 lanes x 8 bf16 ch each), no max pass.
__global__ __launch_bounds__(256) void k_agg12(const int* __restrict__ rp,
                                               const int* __restrict__ csr,
                                               const float* __restrict__ a_s,
                                               const float* __restrict__ a_d,
                                               const __bf16* __restrict__ xh,
                                               const float* __restrict__ lin,
                                               __bf16* __restrict__ out_bf, int n) {
    int wv = (int)((blockIdx.x * blockDim.x + threadIdx.x) >> 6);
    int lane = threadIdx.x & 63;
    int sub = lane >> 5, sl = lane & 31;
    int node = wv * 2 + sub;
    if (node >= n) return;
    int sbase = lane & 32;
    int c0 = sl * 8;
    int h = sl >> 3;
    int start = node ? rp[node - 1] : 0;
    int end = rp[node];
    float ad = a_d[node * 4 + h];
    float z = __expf(lrelu(a_s[node * 4 + h] + ad));
    float acc[8];
    {
        bf16x8 v = *(const bf16x8*)(xh + (size_t)node * 256 + c0);
#pragma unroll
        for (int j = 0; j < 8; j++) acc[j] = z * (float)v[j];
    }
    for (int eb = start; eb < end; eb += 32) {
        int myE = eb + sl;
        int mySrc = (myE < end) ? csr[myE] : 0;
        int cnt = min(32, end - eb);
        for (int j = 0; j < cnt; j++) {
            int s = __shfl(mySrc, sbase + j, 64);
            float w = __expf(lrelu(a_s[s * 4 + h] + ad));
            z += w;
            bf16x8 v = *(const bf16x8*)(xh + (size_t)s * 256 + c0);
#pragma unroll
            for (int q = 0; q < 8; q++) acc[q] += w * (float)v[q];
        }
    }
    float inv = 1.f / (z + 1e-16f);
    const float4* lp = (const float4*)(lin + (size_t)node * 256 + c0);
    float4 l0 = lp[0], l1 = lp[1];
    float lf[8] = {l0.x, l0.y, l0.z, l0.w, l1.x, l1.y, l1.z, l1.w};
    bf16x8 r;
#pragma unroll
    for (int j = 0; j < 8; j++)
        r[j] = (__bf16)fmaxf(acc[j] * inv + lf[j], 0.f);
    *(bf16x8*)(out_bf + (size_t)node * 256 + c0) = r;
}

// bf16 -> fp8 e4m3 (HW cvt), 8 elems/thread
__global__ void k_cvt8(const __bf16* __restrict__ src, unsigned int* __restrict__ dst,
                       int total8) {
    int t = blockIdx.x * blockDim.x + threadIdx.x;
    if (t >= total8) return;
    bf16x8 v = *(const bf16x8*)(src + (size_t)t * 8);
    int p0 = __builtin_amdgcn_cvt_pk_fp8_f32((float)v[0], (float)v[1], 0, false);
    p0 = __builtin_amdgcn_cvt_pk_fp8_f32((float)v[2], (float)v[3], p0, true);
    int p1 = __builtin_amdgcn_cvt_pk_fp8_f32((float)v[4], (float)v[5], 0, false);
    p1 = __builtin_amdgcn_cvt_pk_fp8_f32((float)v[6], (float)v[7], p1, true);
    ((uint2*)dst)[t] = make_uint2((unsigned int)p0, (unsigned int)p1);
}

__device__ __forceinline__ void dec4(unsigned int u, float* f) {
    f32x2 a = __builtin_amdgcn_cvt_pk_f32_fp8(u, false);
    f32x2 b = __builtin_amdgcn_cvt_pk_f32_fp8(u, true);
    f[0] = a[0]; f[1] = a[1]; f[2] = b[0]; f[3] = b[1];
}

// Layer-3 aggregation (HC=512) on fp8 rows; fused head-mean -> mean[n,128]
__global__ __launch_bounds__(256) void k_agg3(const int* __restrict__ rp,
                                              const int* __restrict__ csr,
                                              const float* __restrict__ a_s,
                                              const float* __restrict__ a_d,
                                              const unsigned int* __restrict__ x8,
                                              float* __restrict__ mean, int n) {
    int wv = (int)((blockIdx.x * blockDim.x + threadIdx.x) >> 6);
    int lane = threadIdx.x & 63;
    int sub = lane >> 5, sl = lane & 31;
    int node = wv * 2 + sub;
    if (node >= n) return;
    int sbase = lane & 32;
    int h = sl >> 3;
    int start = node ? rp[node - 1] : 0;
    int end = rp[node];
    float ad = a_d[node * 4 + h];
    float z = __expf(lrelu(a_s[node * 4 + h] + ad));
    float acc[16];
    {
        uint4 u = *(const uint4*)(x8 + (size_t)node * 128 + sl * 4);
        float f[16];
        dec4(u.x, f); dec4(u.y, f + 4); dec4(u.z, f + 8); dec4(u.w, f + 12);
#pragma unroll
        for (int j = 0; j < 16; j++) acc[j] = z * f[j];
    }
    for (int eb = start; eb < end; eb += 32) {
        int myE = eb + sl;
        int mySrc = (myE < end) ? csr[myE] : 0;
        int cnt = min(32, end - eb);
        for (int j = 0; j < cnt; j++) {
            int s = __shfl(mySrc, sbase + j, 64);
            float w = __expf(lrelu(a_s[s * 4 + h] + ad));
            z += w;
            uint4 u = *(const uint4*)(x8 + (size_t)s * 128 + sl * 4);
            float f[16];
            dec4(u.x, f); dec4(u.y, f + 4); dec4(u.z, f + 8); dec4(u.w, f + 12);
#pragma unroll
            for (int q = 0; q < 16; q++) acc[q] += w * f[q];
        }
    }
    float scale = 0.25f / (z + 1e-16f);
#pragma unroll
    for (int j = 0; j < 16; j++) {
        float v = acc[j] * scale;
        v += __shfl_xor(v, 8, 64);
        v += __shfl_xor(v, 16, 64);
        acc[j] = v;
    }
    if ((sl & 24) == 0) {
        float4* op = (float4*)(mean + (size_t)node * 128 + sl * 16);
#pragma unroll
        for (int q = 0; q < 4; q++) {
            float4 o = {acc[4 * q], acc[4 * q + 1], acc[4 * q + 2], acc[4 * q + 3]};
            op[q] = o;
        }
    }
}

// per-graph mean pool (no atomics)
__global__ __launch_bounds__(128) void k_pool(const float* __restrict__ mean,
                                              const float* __restrict__ lin3,
                                              const float* __restrict__ b3,
                                              const int* __restrict__ gs,
                                              float* __restrict__ out) {
    int g = blockIdx.x, c = threadIdx.x;
    int s = gs[g], e = gs[g + 1];
    float acc = 0.f;
    for (int i = s; i < e; i++)
        acc += mean[(size_t)i * 128 + c] + lin3[(size_t)i * 128 + c];
    int cnt = e - s;
    out[(size_t)g * 128 + c] = cnt > 0 ? acc / (float)cnt + b3[c] : 0.f;
}

static inline int cdiv(int a, int b) { return (a + b - 1) / b; }

extern "C" void kernel_launch(void* const* d_in, const int* in_sizes, int n_in,
                              void* d_out, int out_size, void* d_ws, size_t ws_size,
                              hipStream_t stream) {
    const int* x_l = (const int*)d_in[0];
    const int* edge_l = (const int*)d_in[1];
    const int* batch_l = (const int*)d_in[2];
    const int* x_r = (const int*)d_in[3];
    const int* edge_r = (const int*)d_in[4];
    const int* batch_r = (const int*)d_in[5];
    const float* emb = (const float*)d_in[6];
    const float* W1 = (const float*)d_in[7];
    const float* as1 = (const float*)d_in[8];
    const float* ad1 = (const float*)d_in[9];
    const float* b1 = (const float*)d_in[10];
    const float* lw1 = (const float*)d_in[11];
    const float* lb1 = (const float*)d_in[12];
    const float* W2 = (const float*)d_in[13];
    const float* as2 = (const float*)d_in[14];
    const float* ad2 = (const float*)d_in[15];
    const float* b2 = (const float*)d_in[16];
    const float* lw2 = (const float*)d_in[17];
    const float* lb2 = (const float*)d_in[18];
    const float* W3 = (const float*)d_in[19];
    const float* as3 = (const float*)d_in[20];
    const float* ad3 = (const float*)d_in[21];
    const float* b3 = (const float*)d_in[22];
    const float* lw3 = (const float*)d_in[23];
    const float* lb3 = (const float*)d_in[24];

    const int n = in_sizes[0];       // 20000
    const int E = in_sizes[1] / 2;   // 320000

    float* MEAN = (float*)d_ws;                // [n,128]
    float* LIN = MEAN + (size_t)n * 128;       // [n,256]
    float* L3 = LIN + (size_t)n * 256;         // [n,128]
    float* a_s = L3 + (size_t)n * 128;         // [n,4]
    float* a_d = a_s + (size_t)n * 4;
    int* rp = (int*)(a_d + (size_t)n * 4);     // [n]
    int* csr = rp + n;                         // [E]
    int* gs = csr + E;                         // [G+1]
    __bf16* Xbf = (__bf16*)(gs + GG + 1);      // [n,512]
    __bf16* Abf = Xbf + (size_t)n * 512;       // [n,256]
    unsigned int* X8 = (unsigned int*)(Abf + (size_t)n * 256);  // [n,128] fp8
    // combined transposed weights: [W^T | lw^T | attn(16 rows)]
    __bf16* B1t = (__bf16*)(X8 + (size_t)n * 128);   // 528 x 128
    __bf16* B2t = B1t + 528 * 128;                   // 528 x 256
    __bf16* B3t = B2t + 528 * 256;                   // 656 x 256

    const int TB = 256;
    dim3 blk(TB);

    // weight prep (shared by both sides)
    k_wt<<<cdiv(128 * 256, TB), blk, 0, stream>>>(W1, B1t, 128, 256);
    k_wt<<<cdiv(128 * 256, TB), blk, 0, stream>>>(lw1, B1t + 256 * 128, 128, 256);
    k_wattn<<<cdiv(16 * 128, TB), blk, 0, stream>>>(W1, as1, ad1, B1t + 512 * 128, 128, 64);
    k_wt<<<cdiv(256 * 256, TB), blk, 0, stream>>>(W2, B2t, 256, 256);
    k_wt<<<cdiv(256 * 256, TB), blk, 0, stream>>>(lw2, B2t + 256 * 256, 256, 256);
    k_wattn<<<cdiv(16 * 256, TB), blk, 0, stream>>>(W2, as2, ad2, B2t + 512 * 256, 256, 64);
    k_wt<<<cdiv(256 * 512, TB), blk, 0, stream>>>(W3, B3t, 256, 512);
    k_wt<<<cdiv(256 * 128, TB), blk, 0, stream>>>(lw3, B3t + 512 * 256, 256, 128);
    k_wattn<<<cdiv(16 * 256, TB), blk, 0, stream>>>(W3, as3, ad3, B3t + 640 * 256, 256, 128);

    for (int side = 0; side < 2; side++) {
        const int* xi = side ? x_r : x_l;
        const int* edges = side ? edge_r : edge_l;
        const int* batch = side ? batch_r : batch_l;
        float* pool = (float*)d_out + (size_t)side * GG * 128;

        // CSR + graph bounds
        hipMemsetAsync(rp, 0, sizeof(int) * (size_t)n, stream);
        k_hist<<<cdiv(E, TB), blk, 0, stream>>>(edges, E, rp);
        k_scan<<<1, 1024, 0, stream>>>(rp, n);
        k_fill<<<cdiv(E, TB), blk, 0, stream>>>(edges, E, rp, csr);
        k_gbound<<<1, 512, 0, stream>>>(batch, n, gs);

        // embed -> Abf [n,128]
        k_embed_bf<<<cdiv(n * 16, TB), blk, 0, stream>>>(xi, emb, Abf, n);

        // ---- layer 1 (K=128, Mx=256, Ml=256) ----
        k_gemm_all<128><<<dim3(cdiv(n, 64), 2), blk, 0, stream>>>(
            Abf, B1t, n, 256, 256, Xbf, 256, LIN, 256, lb1, b1, a_s, a_d);
        k_agg12<<<cdiv(n, 8), blk, 0, stream>>>(rp, csr, a_s, a_d, Xbf, LIN, Abf, n);

        // ---- layer 2 (K=256, Mx=256, Ml=256) ----
        k_gemm_all<256><<<dim3(cdiv(n, 64), 2), blk, 0, stream>>>(
            Abf, B2t, n, 256, 256, Xbf, 256, LIN, 256, lb2, b2, a_s, a_d);
        k_agg12<<<cdiv(n, 8), blk, 0, stream>>>(rp, csr, a_s, a_d, Xbf, LIN, Abf, n);

        // ---- layer 3 (K=256, Mx=512, Ml=128) ----
        k_gemm_all<256><<<dim3(cdiv(n, 64), 2), blk, 0, stream>>>(
            Abf, B3t, n, 512, 128, Xbf, 512, L3, 128, lb3, nullptr, a_s, a_d);
        k_cvt8<<<cdiv(n * 64, TB), blk, 0, stream>>>(Xbf, X8, n * 64);
        k_agg3<<<cdiv(n, 8), blk, 0, stream>>>(rp, csr, a_s, a_d, X8, MEAN, n);
        k_pool<<<GG, 128, 0, stream>>>(MEAN, L3, b3, gs, pool);
    }
}

// Round 8
// 588.295 us; speedup vs baseline: 1.4816x; 1.2126x over previous
//
#include <hip/hip_runtime.h>

#define GG 256

typedef __bf16 bf16x8 __attribute__((ext_vector_type(8)));
typedef float floatx4 __attribute__((ext_vector_type(4)));
typedef float f32x2 __attribute__((ext_vector_type(2)));

__device__ __forceinline__ float lrelu(float x) { return x > 0.f ? x : 0.2f * x; }

// combined embed over both sides: node<n -> x_l, else x_r
__global__ void k_embed2(const int* __restrict__ xl, const int* __restrict__ xr,
                         const float* __restrict__ emb, __bf16* __restrict__ e,
                         int n, int N2) {
    int t = blockIdx.x * blockDim.x + threadIdx.x;
    if (t >= N2 * 16) return;
    int node = t >> 4, c0 = (t & 15) * 8;
    int xi = (node < n) ? xl[node] : xr[node - n];
    const float4* src = (const float4*)(emb + ((size_t)xi << 7) + c0);
    float4 v0 = src[0], v1 = src[1];
    bf16x8 o = {(__bf16)v0.x, (__bf16)v0.y, (__bf16)v0.z, (__bf16)v0.w,
                (__bf16)v1.x, (__bf16)v1.y, (__bf16)v1.z, (__bf16)v1.w};
    *(bf16x8*)(e + (size_t)node * 128 + c0) = o;
}

// Bt[m*K+k] = bf16(B[k*M+m])
__global__ void k_wt(const float* __restrict__ B, __bf16* __restrict__ Bt, int K, int M) {
    int idx = blockIdx.x * blockDim.x + threadIdx.x;
    if (idx >= K * M) return;
    int k = idx / M, m = idx - k * M;
    Bt[(size_t)m * K + k] = (__bf16)B[idx];
}

// attn proj rows: dst[j*K+k] = j<4: sum_c W[k,j*C+c]*att_s; j 4..8: att_d; 8..16: 0
__global__ void k_wattn(const float* __restrict__ W, const float* __restrict__ att_s,
                        const float* __restrict__ att_d, __bf16* __restrict__ dst,
                        int K, int C) {
    int idx = blockIdx.x * blockDim.x + threadIdx.x;
    if (idx >= 16 * K) return;
    int j = idx / K, k = idx - j * K;
    float v = 0.f;
    if (j < 8) {
        int h = j & 3;
        const float* att = (j < 4) ? att_s : att_d;
        int M = 4 * C;
        for (int c = 0; c < C; c++) v += W[(size_t)k * M + h * C + c] * att[h * C + c];
    }
    dst[(size_t)j * K + k] = (__bf16)v;
}

// All-in-one GEMM: stage full-K A tile (64 rows) in LDS -> hoist A frags to regs
// -> reuse LDS for each 64-col B tile (coalesced) -> MFMA from LDS.
// cols<Mx -> x8 ? fp8 bytes : bf16 xh; [Mx,Mtot) -> lin fp32 +bias1(+bias2);
// mini-tile [Mtot,Mtot+16) -> a_s/a_d (blockIdx.y==1 only).
template <int K>
__global__ __launch_bounds__(256) void k_gemm_all(const __bf16* __restrict__ A,
                                                  const __bf16* __restrict__ Bt,
                                                  int n, int Mx, int Ml,
                                                  __bf16* __restrict__ xh, int ldx,
                                                  unsigned char* __restrict__ x8,
                                                  float* __restrict__ lin, int ldl,
                                                  const float* __restrict__ bias1,
                                                  const float* __restrict__ bias2,
                                                  float* __restrict__ a_s,
                                                  float* __restrict__ a_d) {
    constexpr int KS = K / 32;
    constexpr int LDK = K + 8;
    constexpr int LPR = K / 8;
    __shared__ __bf16 S[64 * LDK];
    int tid = threadIdx.x;
    int wave = tid >> 6, lane = tid & 63;
    int row0 = blockIdx.x * 64;
    for (int i = tid; i < 64 * LPR; i += 256) {
        int r = i / LPR, ko = (i - r * LPR) * 8;
        int gr = row0 + r;
        bf16x8 v = {};
        if (gr < n) v = *(const bf16x8*)(A + (size_t)gr * K + ko);
        *(bf16x8*)&S[r * LDK + ko] = v;
    }
    __syncthreads();
    int kOff = (lane >> 4) * 8;
    int colBase = lane & 15;
    bf16x8 af[KS];
#pragma unroll
    for (int ks = 0; ks < KS; ks++)
        af[ks] = *(const bf16x8*)&S[(wave * 16 + colBase) * LDK + ks * 32 + kOff];
    __syncthreads();
    int Mtot = Mx + Ml;
    int gr0 = row0 + wave * 16 + ((lane >> 4) << 2);
    int half = (Mtot / 128) * 64;
    int c0beg = blockIdx.y * half;
    int c0end = c0beg + half;
    for (int c0 = c0beg; c0 < c0end; c0 += 64) {
        for (int i = tid; i < 64 * LPR; i += 256) {
            int r = i / LPR, ko = (i - r * LPR) * 8;
            *(bf16x8*)&S[r * LDK + ko] = *(const bf16x8*)(Bt + (size_t)(c0 + r) * K + ko);
        }
        __syncthreads();
        floatx4 acc[4] = {};
#pragma unroll
        for (int ct = 0; ct < 4; ct++) {
#pragma unroll
            for (int ks = 0; ks < KS; ks++) {
                bf16x8 bf = *(const bf16x8*)&S[(ct * 16 + colBase) * LDK + ks * 32 + kOff];
                acc[ct] = __builtin_amdgcn_mfma_f32_16x16x32_bf16(af[ks], bf, acc[ct], 0, 0, 0);
            }
        }
        __syncthreads();
        if (c0 < Mx) {
            if (x8) {  // fp8-byte output (layer 3)
#pragma unroll
                for (int r = 0; r < 4; r++) {
                    int gr = gr0 + r;
                    if (gr >= n) continue;
#pragma unroll
                    for (int ct = 0; ct < 4; ct++) {
                        float v = acc[ct][r];
                        int p = __builtin_amdgcn_cvt_pk_fp8_f32(v, v, 0, false);
                        x8[(size_t)gr * ldx + c0 + ct * 16 + colBase] = (unsigned char)(p & 0xff);
                    }
                }
            } else {
#pragma unroll
                for (int r = 0; r < 4; r++) {
                    int gr = gr0 + r;
                    if (gr >= n) continue;
#pragma unroll
                    for (int ct = 0; ct < 4; ct++)
                        xh[(size_t)gr * ldx + c0 + ct * 16 + colBase] = (__bf16)acc[ct][r];
                }
            }
        } else {
#pragma unroll
            for (int r = 0; r < 4; r++) {
                int gr = gr0 + r;
                if (gr >= n) continue;
#pragma unroll
                for (int ct = 0; ct < 4; ct++) {
                    int c2 = c0 + ct * 16 + colBase - Mx;
                    float v = acc[ct][r] + bias1[c2];
                    if (bias2) v += bias2[c2];
                    lin[(size_t)gr * ldl + c2] = v;
                }
            }
        }
    }
    if (blockIdx.y == 1) {  // attn mini-tile: 4 a_s, 4 a_d cols (L2-hot)
        floatx4 acc = {};
        const __bf16* bp = Bt + (size_t)(Mtot + colBase) * K + kOff;
#pragma unroll
        for (int ks = 0; ks < KS; ks++) {
            bf16x8 bf = *(const bf16x8*)(bp + ks * 32);
            acc = __builtin_amdgcn_mfma_f32_16x16x32_bf16(af[ks], bf, acc, 0, 0, 0);
        }
        if (colBase < 8) {
            float* dst = (colBase < 4) ? a_s : a_d;
            int h = colBase & 3;
#pragma unroll
            for (int r = 0; r < 4; r++) {
                int gr = gr0 + r;
                if (gr < n) dst[gr * 4 + h] = acc[r];
            }
        }
    }
}

// ---- combined-CSR build over both sides (side-1 ids offset by n) ----
__global__ void k_hist2(const int* __restrict__ el, const int* __restrict__ er,
                        int E, int n, int* __restrict__ deg) {
    int e = blockIdx.x * blockDim.x + threadIdx.x;
    if (e >= 2 * E) return;
    int d = (e < E) ? el[E + e] : er[E + (e - E)] + n;
    atomicAdd(&deg[d], 1);
}

__global__ __launch_bounds__(1024) void k_scan(int* __restrict__ rp, int n) {
    __shared__ int wsum[16];
    __shared__ int s_carry;
    int lane = threadIdx.x & 63, wid = threadIdx.x >> 6;
    if (threadIdx.x == 0) s_carry = 0;
    __syncthreads();
    for (int base = 0; base < n; base += 1024) {
        int i = base + threadIdx.x;
        int v = (i < n) ? rp[i] : 0;
        int inc = v;
#pragma unroll
        for (int off = 1; off < 64; off <<= 1) {
            int t = __shfl_up(inc, off, 64);
            if (lane >= off) inc += t;
        }
        if (lane == 63) wsum[wid] = inc;
        __syncthreads();
        int carry = s_carry;
        __syncthreads();
        if (wid == 0) {
            int wv = (lane < 16) ? wsum[lane] : 0;
            int winc = wv;
#pragma unroll
            for (int off = 1; off < 16; off <<= 1) {
                int t = __shfl_up(winc, off, 64);
                if (lane >= off) winc += t;
            }
            if (lane < 16) wsum[lane] = winc - wv;
            if (lane == 15) s_carry = carry + winc;
        }
        __syncthreads();
        if (i < n) rp[i] = carry + wsum[wid] + (inc - v);
        __syncthreads();
    }
}

__global__ void k_fill2(const int* __restrict__ el, const int* __restrict__ er,
                        int E, int n, int* __restrict__ rp, int* __restrict__ csr) {
    int e = blockIdx.x * blockDim.x + threadIdx.x;
    if (e >= 2 * E) return;
    int d, s;
    if (e < E) { s = el[e]; d = el[E + e]; }
    else       { s = er[e - E] + n; d = er[E + (e - E)] + n; }
    int pos = atomicAdd(&rp[d], 1);
    csr[pos] = s;
}

// combined graph bounds: gs[g] for g in [0,2G], side split at G
__global__ void k_gbound2(const int* __restrict__ bl, const int* __restrict__ br,
                          int n, int* __restrict__ gs) {
    int g = blockIdx.x * blockDim.x + threadIdx.x;
    if (g > 2 * GG) return;
    if (g == 2 * GG) { gs[g] = 2 * n; return; }
    const int* b = (g < GG) ? bl : br;
    int tgt = (g < GG) ? g : g - GG;
    int off = (g < GG) ? 0 : n;
    int lo = 0, hi = n;
    while (lo < hi) {
        int mid = (lo + hi) >> 1;
        if (b[mid] < tgt) lo = mid + 1; else hi = mid;
    }
    gs[g] = off + lo;
}

// Layers 1/2 aggregation: 2 nodes/wave, 1-ahead row prefetch, no max pass.
__global__ __launch_bounds__(256) void k_agg12(const int* __restrict__ rp,
                                               const int* __restrict__ csr,
                                               const float* __restrict__ a_s,
                                               const float* __restrict__ a_d,
                                               const __bf16* __restrict__ xh,
                                               const float* __restrict__ lin,
                                               __bf16* __restrict__ out_bf, int n) {
    int wv = (int)((blockIdx.x * blockDim.x + threadIdx.x) >> 6);
    int lane = threadIdx.x & 63;
    int sub = lane >> 5, sl = lane & 31;
    int node = wv * 2 + sub;
    if (node >= n) return;
    int sbase = lane & 32;
    int c0 = sl * 8;
    int h = sl >> 3;
    int start = node ? rp[node - 1] : 0;
    int end = rp[node];
    float ad = a_d[node * 4 + h];
    float z = __expf(lrelu(a_s[node * 4 + h] + ad));
    float acc[8];
    {
        bf16x8 v = *(const bf16x8*)(xh + (size_t)node * 256 + c0);
#pragma unroll
        for (int j = 0; j < 8; j++) acc[j] = z * (float)v[j];
    }
    for (int eb = start; eb < end; eb += 32) {
        int myE = eb + sl;
        int mySrc = (myE < end) ? csr[myE] : 0;
        int cnt = min(32, end - eb);
        int sj = __shfl(mySrc, sbase, 64);
        bf16x8 v = *(const bf16x8*)(xh + (size_t)sj * 256 + c0);
        for (int j = 0; j < cnt; j++) {
            bf16x8 vc = v;
            float as = a_s[sj * 4 + h];
            if (j + 1 < cnt) {
                sj = __shfl(mySrc, sbase + j + 1, 64);
                v = *(const bf16x8*)(xh + (size_t)sj * 256 + c0);
            }
            float w = __expf(lrelu(as + ad));
            z += w;
#pragma unroll
            for (int q = 0; q < 8; q++) acc[q] += w * (float)vc[q];
        }
    }
    float inv = 1.f / (z + 1e-16f);
    const float4* lp = (const float4*)(lin + (size_t)node * 256 + c0);
    float4 l0 = lp[0], l1 = lp[1];
    float lf[8] = {l0.x, l0.y, l0.z, l0.w, l1.x, l1.y, l1.z, l1.w};
    bf16x8 r;
#pragma unroll
    for (int j = 0; j < 8; j++)
        r[j] = (__bf16)fmaxf(acc[j] * inv + lf[j], 0.f);
    *(bf16x8*)(out_bf + (size_t)node * 256 + c0) = r;
}

__device__ __forceinline__ void dec4(unsigned int u, float* f) {
    f32x2 a = __builtin_amdgcn_cvt_pk_f32_fp8(u, false);
    f32x2 b = __builtin_amdgcn_cvt_pk_f32_fp8(u, true);
    f[0] = a[0]; f[1] = a[1]; f[2] = b[0]; f[3] = b[1];
}

// Layer-3 aggregation (HC=512) on fp8 rows; 1-ahead prefetch; head-mean -> mean[n,128]
__global__ __launch_bounds__(256) void k_agg3(const int* __restrict__ rp,
                                              const int* __restrict__ csr,
                                              const float* __restrict__ a_s,
                                              const float* __restrict__ a_d,
                                              const unsigned int* __restrict__ x8,
                                              float* __restrict__ mean, int n) {
    int wv = (int)((blockIdx.x * blockDim.x + threadIdx.x) >> 6);
    int lane = threadIdx.x & 63;
    int sub = lane >> 5, sl = lane & 31;
    int node = wv * 2 + sub;
    if (node >= n) return;
    int sbase = lane & 32;
    int h = sl >> 3;
    int start = node ? rp[node - 1] : 0;
    int end = rp[node];
    float ad = a_d[node * 4 + h];
    float z = __expf(lrelu(a_s[node * 4 + h] + ad));
    float acc[16];
    {
        uint4 u = *(const uint4*)(x8 + (size_t)node * 128 + sl * 4);
        float f[16];
        dec4(u.x, f); dec4(u.y, f + 4); dec4(u.z, f + 8); dec4(u.w, f + 12);
#pragma unroll
        for (int j = 0; j < 16; j++) acc[j] = z * f[j];
    }
    for (int eb = start; eb < end; eb += 32) {
        int myE = eb + sl;
        int mySrc = (myE < end) ? csr[myE] : 0;
        int cnt = min(32, end - eb);
        int sj = __shfl(mySrc, sbase, 64);
        uint4 u = *(const uint4*)(x8 + (size_t)sj * 128 + sl * 4);
        for (int j = 0; j < cnt; j++) {
            uint4 uc = u;
            float as = a_s[sj * 4 + h];
            if (j + 1 < cnt) {
                sj = __shfl(mySrc, sbase + j + 1, 64);
                u = *(const uint4*)(x8 + (size_t)sj * 128 + sl * 4);
            }
            float w = __expf(lrelu(as + ad));
            z += w;
            float f[16];
            dec4(uc.x, f); dec4(uc.y, f + 4); dec4(uc.z, f + 8); dec4(uc.w, f + 12);
#pragma unroll
            for (int q = 0; q < 16; q++) acc[q] += w * f[q];
        }
    }
    float scale = 0.25f / (z + 1e-16f);
#pragma unroll
    for (int j = 0; j < 16; j++) {
        float v = acc[j] * scale;
        v += __shfl_xor(v, 8, 64);
        v += __shfl_xor(v, 16, 64);
        acc[j] = v;
    }
    if ((sl & 24) == 0) {
        float4* op = (float4*)(mean + (size_t)node * 128 + sl * 16);
#pragma unroll
        for (int q = 0; q < 4; q++) {
            float4 o = {acc[4 * q], acc[4 * q + 1], acc[4 * q + 2], acc[4 * q + 3]};
            op[q] = o;
        }
    }
}

// per-graph mean pool over combined graphs (2G blocks), direct to d_out
__global__ __launch_bounds__(128) void k_pool(const float* __restrict__ mean,
                                              const float* __restrict__ lin3,
                                              const float* __restrict__ b3,
                                              const int* __restrict__ gs,
                                              float* __restrict__ out) {
    int g = blockIdx.x, c = threadIdx.x;
    int s = gs[g], e = gs[g + 1];
    float acc = 0.f;
    for (int i = s; i < e; i++)
        acc += mean[(size_t)i * 128 + c] + lin3[(size_t)i * 128 + c];
    int cnt = e - s;
    out[(size_t)g * 128 + c] = cnt > 0 ? acc / (float)cnt + b3[c] : 0.f;
}

static inline int cdiv(int a, int b) { return (a + b - 1) / b; }

extern "C" void kernel_launch(void* const* d_in, const int* in_sizes, int n_in,
                              void* d_out, int out_size, void* d_ws, size_t ws_size,
                              hipStream_t stream) {
    const int* x_l = (const int*)d_in[0];
    const int* edge_l = (const int*)d_in[1];
    const int* batch_l = (const int*)d_in[2];
    const int* x_r = (const int*)d_in[3];
    const int* edge_r = (const int*)d_in[4];
    const int* batch_r = (const int*)d_in[5];
    const float* emb = (const float*)d_in[6];
    const float* W1 = (const float*)d_in[7];
    const float* as1 = (const float*)d_in[8];
    const float* ad1 = (const float*)d_in[9];
    const float* b1 = (const float*)d_in[10];
    const float* lw1 = (const float*)d_in[11];
    const float* lb1 = (const float*)d_in[12];
    const float* W2 = (const float*)d_in[13];
    const float* as2 = (const float*)d_in[14];
    const float* ad2 = (const float*)d_in[15];
    const float* b2 = (const float*)d_in[16];
    const float* lw2 = (const float*)d_in[17];
    const float* lb2 = (const float*)d_in[18];
    const float* W3 = (const float*)d_in[19];
    const float* as3 = (const float*)d_in[20];
    const float* ad3 = (const float*)d_in[21];
    const float* b3 = (const float*)d_in[22];
    const float* lw3 = (const float*)d_in[23];
    const float* lb3 = (const float*)d_in[24];

    const int n = in_sizes[0];       // 20000
    const int E = in_sizes[1] / 2;   // 320000
    const int N2 = 2 * n;

    float* MEAN = (float*)d_ws;                // [N2,128]
    float* LIN = MEAN + (size_t)N2 * 128;      // [N2,256]
    float* L3 = LIN + (size_t)N2 * 256;        // [N2,128]
    float* a_s = L3 + (size_t)N2 * 128;        // [N2,4]
    float* a_d = a_s + (size_t)N2 * 4;
    int* rp = (int*)(a_d + (size_t)N2 * 4);    // [N2]
    int* csr = rp + N2;                        // [2E]
    int* gs = csr + 2 * E;                     // [2G+1]
    __bf16* Xbf = (__bf16*)(gs + 2 * GG + 4);  // [N2,256]
    __bf16* Abf = Xbf + (size_t)N2 * 256;      // [N2,256]
    unsigned int* X8 = (unsigned int*)(Abf + (size_t)N2 * 256);  // [N2,128] fp8x4
    __bf16* B1t = (__bf16*)(X8 + (size_t)N2 * 128);  // 528 x 128
    __bf16* B2t = B1t + 528 * 128;                   // 528 x 256
    __bf16* B3t = B2t + 528 * 256;                   // 656 x 256

    const int TB = 256;
    dim3 blk(TB);

    // weight prep (shared by both sides)
    k_wt<<<cdiv(128 * 256, TB), blk, 0, stream>>>(W1, B1t, 128, 256);
    k_wt<<<cdiv(128 * 256, TB), blk, 0, stream>>>(lw1, B1t + 256 * 128, 128, 256);
    k_wattn<<<cdiv(16 * 128, TB), blk, 0, stream>>>(W1, as1, ad1, B1t + 512 * 128, 128, 64);
    k_wt<<<cdiv(256 * 256, TB), blk, 0, stream>>>(W2, B2t, 256, 256);
    k_wt<<<cdiv(256 * 256, TB), blk, 0, stream>>>(lw2, B2t + 256 * 256, 256, 256);
    k_wattn<<<cdiv(16 * 256, TB), blk, 0, stream>>>(W2, as2, ad2, B2t + 512 * 256, 256, 64);
    k_wt<<<cdiv(256 * 512, TB), blk, 0, stream>>>(W3, B3t, 256, 512);
    k_wt<<<cdiv(256 * 128, TB), blk, 0, stream>>>(lw3, B3t + 512 * 256, 256, 128);
    k_wattn<<<cdiv(16 * 256, TB), blk, 0, stream>>>(W3, as3, ad3, B3t + 640 * 256, 256, 128);

    // combined CSR + graph bounds (once for all 3 layers, both sides)
    hipMemsetAsync(rp, 0, sizeof(int) * (size_t)N2, stream);
    k_hist2<<<cdiv(2 * E, TB), blk, 0, stream>>>(edge_l, edge_r, E, n, rp);
    k_scan<<<1, 1024, 0, stream>>>(rp, N2);
    k_fill2<<<cdiv(2 * E, TB), blk, 0, stream>>>(edge_l, edge_r, E, n, rp, csr);
    k_gbound2<<<cdiv(2 * GG + 1, 512), 512, 0, stream>>>(batch_l, batch_r, n, gs);

    // embed both sides -> Abf [N2,128]
    k_embed2<<<cdiv(N2 * 16, TB), blk, 0, stream>>>(x_l, x_r, emb, Abf, n, N2);

    // ---- layer 1 (K=128, Mx=256, Ml=256) ----
    k_gemm_all<128><<<dim3(cdiv(N2, 64), 2), blk, 0, stream>>>(
        Abf, B1t, N2, 256, 256, Xbf, 256, nullptr, LIN, 256, lb1, b1, a_s, a_d);
    k_agg12<<<cdiv(N2, 8), blk, 0, stream>>>(rp, csr, a_s, a_d, Xbf, LIN, Abf, N2);

    // ---- layer 2 (K=256, Mx=256, Ml=256) ----
    k_gemm_all<256><<<dim3(cdiv(N2, 64), 2), blk, 0, stream>>>(
        Abf, B2t, N2, 256, 256, Xbf, 256, nullptr, LIN, 256, lb2, b2, a_s, a_d);
    k_agg12<<<cdiv(N2, 8), blk, 0, stream>>>(rp, csr, a_s, a_d, Xbf, LIN, Abf, N2);

    // ---- layer 3 (K=256, Mx=512 -> fp8 bytes, Ml=128) ----
    k_gemm_all<256><<<dim3(cdiv(N2, 64), 2), blk, 0, stream>>>(
        Abf, B3t, N2, 512, 128, nullptr, 512, (unsigned char*)X8, L3, 128, lb3, nullptr, a_s, a_d);
    k_agg3<<<cdiv(N2, 8), blk, 0, stream>>>(rp, csr, a_s, a_d, X8, MEAN, N2);
    k_pool<<<2 * GG, 128, 0, stream>>>(MEAN, L3, b3, gs, (float*)d_out);
}

// Round 9
// 554.807 us; speedup vs baseline: 1.5710x; 1.0604x over previous
//
#include <hip/hip_runtime.h>

#define GG 256

typedef __bf16 bf16x8 __attribute__((ext_vector_type(8)));
typedef float floatx4 __attribute__((ext_vector_type(4)));
typedef float f32x2 __attribute__((ext_vector_type(2)));

__device__ __forceinline__ float lrelu(float x) { return x > 0.f ? x : 0.2f * x; }

// combined embed over both sides: node<n -> x_l, else x_r
__global__ void k_embed2(const int* __restrict__ xl, const int* __restrict__ xr,
                         const float* __restrict__ emb, __bf16* __restrict__ e,
                         int n, int N2) {
    int t = blockIdx.x * blockDim.x + threadIdx.x;
    if (t >= N2 * 16) return;
    int node = t >> 4, c0 = (t & 15) * 8;
    int xi = (node < n) ? xl[node] : xr[node - n];
    const float4* src = (const float4*)(emb + ((size_t)xi << 7) + c0);
    float4 v0 = src[0], v1 = src[1];
    bf16x8 o = {(__bf16)v0.x, (__bf16)v0.y, (__bf16)v0.z, (__bf16)v0.w,
                (__bf16)v1.x, (__bf16)v1.y, (__bf16)v1.z, (__bf16)v1.w};
    *(bf16x8*)(e + (size_t)node * 128 + c0) = o;
}

// Bt[m*K+k] = bf16(B[k*M+m])
__global__ void k_wt(const float* __restrict__ B, __bf16* __restrict__ Bt, int K, int M) {
    int idx = blockIdx.x * blockDim.x + threadIdx.x;
    if (idx >= K * M) return;
    int k = idx / M, m = idx - k * M;
    Bt[(size_t)m * K + k] = (__bf16)B[idx];
}

// attn proj rows: dst[j*K+k] = j<4: sum_c W[k,j*C+c]*att_s; j 4..8: att_d; 8..16: 0
__global__ void k_wattn(const float* __restrict__ W, const float* __restrict__ att_s,
                        const float* __restrict__ att_d, __bf16* __restrict__ dst,
                        int K, int C) {
    int idx = blockIdx.x * blockDim.x + threadIdx.x;
    if (idx >= 16 * K) return;
    int j = idx / K, k = idx - j * K;
    float v = 0.f;
    if (j < 8) {
        int h = j & 3;
        const float* att = (j < 4) ? att_s : att_d;
        int M = 4 * C;
        for (int c = 0; c < C; c++) v += W[(size_t)k * M + h * C + c] * att[h * C + c];
    }
    dst[(size_t)j * K + k] = (__bf16)v;
}

// All-in-one GEMM: stage full-K A tile (64 rows) in LDS -> hoist A frags to regs
// -> reuse LDS for each 64-col B tile (coalesced) -> MFMA from LDS.
// cols<Mx -> fp8 e4m3 bytes into x8 (ld=ldx); [Mx,Mtot) -> lin fp32 +bias1(+bias2);
// mini-tile [Mtot,Mtot+16) -> a_s/a_d fp32 (blockIdx.y==1 only).
template <int K>
__global__ __launch_bounds__(256) void k_gemm_all(const __bf16* __restrict__ A,
                                                  const __bf16* __restrict__ Bt,
                                                  int n, int Mx, int Ml,
                                                  unsigned char* __restrict__ x8, int ldx,
                                                  float* __restrict__ lin, int ldl,
                                                  const float* __restrict__ bias1,
                                                  const float* __restrict__ bias2,
                                                  float* __restrict__ a_s,
                                                  float* __restrict__ a_d) {
    constexpr int KS = K / 32;
    constexpr int LDK = K + 8;
    constexpr int LPR = K / 8;
    __shared__ __bf16 S[64 * LDK];
    int tid = threadIdx.x;
    int wave = tid >> 6, lane = tid & 63;
    int row0 = blockIdx.x * 64;
    for (int i = tid; i < 64 * LPR; i += 256) {
        int r = i / LPR, ko = (i - r * LPR) * 8;
        int gr = row0 + r;
        bf16x8 v = {};
        if (gr < n) v = *(const bf16x8*)(A + (size_t)gr * K + ko);
        *(bf16x8*)&S[r * LDK + ko] = v;
    }
    __syncthreads();
    int kOff = (lane >> 4) * 8;
    int colBase = lane & 15;
    bf16x8 af[KS];
#pragma unroll
    for (int ks = 0; ks < KS; ks++)
        af[ks] = *(const bf16x8*)&S[(wave * 16 + colBase) * LDK + ks * 32 + kOff];
    __syncthreads();
    int Mtot = Mx + Ml;
    int gr0 = row0 + wave * 16 + ((lane >> 4) << 2);
    int half = (Mtot / 128) * 64;
    int c0beg = blockIdx.y * half;
    int c0end = c0beg + half;
    for (int c0 = c0beg; c0 < c0end; c0 += 64) {
        for (int i = tid; i < 64 * LPR; i += 256) {
            int r = i / LPR, ko = (i - r * LPR) * 8;
            *(bf16x8*)&S[r * LDK + ko] = *(const bf16x8*)(Bt + (size_t)(c0 + r) * K + ko);
        }
        __syncthreads();
        floatx4 acc[4] = {};
#pragma unroll
        for (int ct = 0; ct < 4; ct++) {
#pragma unroll
            for (int ks = 0; ks < KS; ks++) {
                bf16x8 bf = *(const bf16x8*)&S[(ct * 16 + colBase) * LDK + ks * 32 + kOff];
                acc[ct] = __builtin_amdgcn_mfma_f32_16x16x32_bf16(af[ks], bf, acc[ct], 0, 0, 0);
            }
        }
        __syncthreads();
        if (c0 < Mx) {  // fp8-byte feature output (all layers)
#pragma unroll
            for (int r = 0; r < 4; r++) {
                int gr = gr0 + r;
                if (gr >= n) continue;
#pragma unroll
                for (int ct = 0; ct < 4; ct++) {
                    float v = acc[ct][r];
                    int p = __builtin_amdgcn_cvt_pk_fp8_f32(v, v, 0, false);
                    x8[(size_t)gr * ldx + c0 + ct * 16 + colBase] = (unsigned char)(p & 0xff);
                }
            }
        } else {
#pragma unroll
            for (int r = 0; r < 4; r++) {
                int gr = gr0 + r;
                if (gr >= n) continue;
#pragma unroll
                for (int ct = 0; ct < 4; ct++) {
                    int c2 = c0 + ct * 16 + colBase - Mx;
                    float v = acc[ct][r] + bias1[c2];
                    if (bias2) v += bias2[c2];
                    lin[(size_t)gr * ldl + c2] = v;
                }
            }
        }
    }
    if (blockIdx.y == 1) {  // attn mini-tile: 4 a_s, 4 a_d cols (L2-hot)
        floatx4 acc = {};
        const __bf16* bp = Bt + (size_t)(Mtot + colBase) * K + kOff;
#pragma unroll
        for (int ks = 0; ks < KS; ks++) {
            bf16x8 bf = *(const bf16x8*)(bp + ks * 32);
            acc = __builtin_amdgcn_mfma_f32_16x16x32_bf16(af[ks], bf, acc, 0, 0, 0);
        }
        if (colBase < 8) {
            float* dst = (colBase < 4) ? a_s : a_d;
            int h = colBase & 3;
#pragma unroll
            for (int r = 0; r < 4; r++) {
                int gr = gr0 + r;
                if (gr < n) dst[gr * 4 + h] = acc[r];
            }
        }
    }
}

// ---- combined-CSR build over both sides (side-1 ids offset by n) ----
__global__ void k_hist2(const int* __restrict__ el, const int* __restrict__ er,
                        int E, int n, int* __restrict__ deg) {
    int e = blockIdx.x * blockDim.x + threadIdx.x;
    if (e >= 2 * E) return;
    int d = (e < E) ? el[E + e] : er[E + (e - E)] + n;
    atomicAdd(&deg[d], 1);
}

__global__ __launch_bounds__(1024) void k_scan(int* __restrict__ rp, int n) {
    __shared__ int wsum[16];
    __shared__ int s_carry;
    int lane = threadIdx.x & 63, wid = threadIdx.x >> 6;
    if (threadIdx.x == 0) s_carry = 0;
    __syncthreads();
    for (int base = 0; base < n; base += 1024) {
        int i = base + threadIdx.x;
        int v = (i < n) ? rp[i] : 0;
        int inc = v;
#pragma unroll
        for (int off = 1; off < 64; off <<= 1) {
            int t = __shfl_up(inc, off, 64);
            if (lane >= off) inc += t;
        }
        if (lane == 63) wsum[wid] = inc;
        __syncthreads();
        int carry = s_carry;
        __syncthreads();
        if (wid == 0) {
            int wv = (lane < 16) ? wsum[lane] : 0;
            int winc = wv;
#pragma unroll
            for (int off = 1; off < 16; off <<= 1) {
                int t = __shfl_up(winc, off, 64);
                if (lane >= off) winc += t;
            }
            if (lane < 16) wsum[lane] = winc - wv;
            if (lane == 15) s_carry = carry + winc;
        }
        __syncthreads();
        if (i < n) rp[i] = carry + wsum[wid] + (inc - v);
        __syncthreads();
    }
}

__global__ void k_fill2(const int* __restrict__ el, const int* __restrict__ er,
                        int E, int n, int* __restrict__ rp, int* __restrict__ csr) {
    int e = blockIdx.x * blockDim.x + threadIdx.x;
    if (e >= 2 * E) return;
    int d, s;
    if (e < E) { s = el[e]; d = el[E + e]; }
    else       { s = er[e - E] + n; d = er[E + (e - E)] + n; }
    int pos = atomicAdd(&rp[d], 1);
    csr[pos] = s;
}

// combined graph bounds: gs[g] for g in [0,2G], side split at G
__global__ void k_gbound2(const int* __restrict__ bl, const int* __restrict__ br,
                          int n, int* __restrict__ gs) {
    int g = blockIdx.x * blockDim.x + threadIdx.x;
    if (g > 2 * GG) return;
    if (g == 2 * GG) { gs[g] = 2 * n; return; }
    const int* b = (g < GG) ? bl : br;
    int tgt = (g < GG) ? g : g - GG;
    int off = (g < GG) ? 0 : n;
    int lo = 0, hi = n;
    while (lo < hi) {
        int mid = (lo + hi) >> 1;
        if (b[mid] < tgt) lo = mid + 1; else hi = mid;
    }
    gs[g] = off + lo;
}

__device__ __forceinline__ void dec4(unsigned int u, float* f) {
    f32x2 a = __builtin_amdgcn_cvt_pk_f32_fp8(u, false);
    f32x2 b = __builtin_amdgcn_cvt_pk_f32_fp8(u, true);
    f[0] = a[0]; f[1] = a[1]; f[2] = b[0]; f[3] = b[1];
}

// Layers 1/2 aggregation on fp8 rows (256 B): 2 nodes/wave, 1-ahead prefetch.
// out_bf = bf16(relu(agg/z + lin))
__global__ __launch_bounds__(256) void k_agg12(const int* __restrict__ rp,
                                               const int* __restrict__ csr,
                                               const float* __restrict__ a_s,
                                               const float* __restrict__ a_d,
                                               const unsigned char* __restrict__ x8,
                                               const float* __restrict__ lin,
                                               __bf16* __restrict__ out_bf, int n) {
    int wv = (int)((blockIdx.x * blockDim.x + threadIdx.x) >> 6);
    int lane = threadIdx.x & 63;
    int sub = lane >> 5, sl = lane & 31;
    int node = wv * 2 + sub;
    if (node >= n) return;
    int sbase = lane & 32;
    int c0 = sl * 8;   // 8 fp8 ch per lane
    int h = sl >> 3;
    int start = node ? rp[node - 1] : 0;
    int end = rp[node];
    float ad = a_d[node * 4 + h];
    float z = __expf(lrelu(a_s[node * 4 + h] + ad));
    float acc[8];
    {
        uint2 u = *(const uint2*)(x8 + (size_t)node * 256 + c0);
        float f[8];
        dec4(u.x, f); dec4(u.y, f + 4);
#pragma unroll
        for (int j = 0; j < 8; j++) acc[j] = z * f[j];
    }
    for (int eb = start; eb < end; eb += 32) {
        int myE = eb + sl;
        int mySrc = (myE < end) ? csr[myE] : 0;
        int cnt = min(32, end - eb);
        int sj = __shfl(mySrc, sbase, 64);
        uint2 u = *(const uint2*)(x8 + (size_t)sj * 256 + c0);
        for (int j = 0; j < cnt; j++) {
            uint2 uc = u;
            float as = a_s[sj * 4 + h];
            if (j + 1 < cnt) {
                sj = __shfl(mySrc, sbase + j + 1, 64);
                u = *(const uint2*)(x8 + (size_t)sj * 256 + c0);
            }
            float w = __expf(lrelu(as + ad));
            z += w;
            float f[8];
            dec4(uc.x, f); dec4(uc.y, f + 4);
#pragma unroll
            for (int q = 0; q < 8; q++) acc[q] += w * f[q];
        }
    }
    float inv = 1.f / (z + 1e-16f);
    const float4* lp = (const float4*)(lin + (size_t)node * 256 + c0);
    float4 l0 = lp[0], l1 = lp[1];
    float lf[8] = {l0.x, l0.y, l0.z, l0.w, l1.x, l1.y, l1.z, l1.w};
    bf16x8 r;
#pragma unroll
    for (int j = 0; j < 8; j++)
        r[j] = (__bf16)fmaxf(acc[j] * inv + lf[j], 0.f);
    *(bf16x8*)(out_bf + (size_t)node * 256 + c0) = r;
}

// Layer-3 aggregation (HC=512) on fp8 rows; 1-ahead prefetch; head-mean -> mean[n,128]
__global__ __launch_bounds__(256) void k_agg3(const int* __restrict__ rp,
                                              const int* __restrict__ csr,
                                              const float* __restrict__ a_s,
                                              const float* __restrict__ a_d,
                                              const unsigned int* __restrict__ x8,
                                              float* __restrict__ mean, int n) {
    int wv = (int)((blockIdx.x * blockDim.x + threadIdx.x) >> 6);
    int lane = threadIdx.x & 63;
    int sub = lane >> 5, sl = lane & 31;
    int node = wv * 2 + sub;
    if (node >= n) return;
    int sbase = lane & 32;
    int h = sl >> 3;
    int start = node ? rp[node - 1] : 0;
    int end = rp[node];
    float ad = a_d[node * 4 + h];
    float z = __expf(lrelu(a_s[node * 4 + h] + ad));
    float acc[16];
    {
        uint4 u = *(const uint4*)(x8 + (size_t)node * 128 + sl * 4);
        float f[16];
        dec4(u.x, f); dec4(u.y, f + 4); dec4(u.z, f + 8); dec4(u.w, f + 12);
#pragma unroll
        for (int j = 0; j < 16; j++) acc[j] = z * f[j];
    }
    for (int eb = start; eb < end; eb += 32) {
        int myE = eb + sl;
        int mySrc = (myE < end) ? csr[myE] : 0;
        int cnt = min(32, end - eb);
        int sj = __shfl(mySrc, sbase, 64);
        uint4 u = *(const uint4*)(x8 + (size_t)sj * 128 + sl * 4);
        for (int j = 0; j < cnt; j++) {
            uint4 uc = u;
            float as = a_s[sj * 4 + h];
            if (j + 1 < cnt) {
                sj = __shfl(mySrc, sbase + j + 1, 64);
                u = *(const uint4*)(x8 + (size_t)sj * 128 + sl * 4);
            }
            float w = __expf(lrelu(as + ad));
            z += w;
            float f[16];
            dec4(uc.x, f); dec4(uc.y, f + 4); dec4(uc.z, f + 8); dec4(uc.w, f + 12);
#pragma unroll
            for (int q = 0; q < 16; q++) acc[q] += w * f[q];
        }
    }
    float scale = 0.25f / (z + 1e-16f);
#pragma unroll
    for (int j = 0; j < 16; j++) {
        float v = acc[j] * scale;
        v += __shfl_xor(v, 8, 64);
        v += __shfl_xor(v, 16, 64);
        acc[j] = v;
    }
    if ((sl & 24) == 0) {
        float4* op = (float4*)(mean + (size_t)node * 128 + sl * 16);
#pragma unroll
        for (int q = 0; q < 4; q++) {
            float4 o = {acc[4 * q], acc[4 * q + 1], acc[4 * q + 2], acc[4 * q + 3]};
            op[q] = o;
        }
    }
}

// per-graph mean pool over combined graphs (2G blocks), direct to d_out
__global__ __launch_bounds__(128) void k_pool(const float* __restrict__ mean,
                                              const float* __restrict__ lin3,
                                              const float* __restrict__ b3,
                                              const int* __restrict__ gs,
                                              float* __restrict__ out) {
    int g = blockIdx.x, c = threadIdx.x;
    int s = gs[g], e = gs[g + 1];
    float acc = 0.f;
    for (int i = s; i < e; i++)
        acc += mean[(size_t)i * 128 + c] + lin3[(size_t)i * 128 + c];
    int cnt = e - s;
    out[(size_t)g * 128 + c] = cnt > 0 ? acc / (float)cnt + b3[c] : 0.f;
}

static inline int cdiv(int a, int b) { return (a + b - 1) / b; }

extern "C" void kernel_launch(void* const* d_in, const int* in_sizes, int n_in,
                              void* d_out, int out_size, void* d_ws, size_t ws_size,
                              hipStream_t stream) {
    const int* x_l = (const int*)d_in[0];
    const int* edge_l = (const int*)d_in[1];
    const int* batch_l = (const int*)d_in[2];
    const int* x_r = (const int*)d_in[3];
    const int* edge_r = (const int*)d_in[4];
    const int* batch_r = (const int*)d_in[5];
    const float* emb = (const float*)d_in[6];
    const float* W1 = (const float*)d_in[7];
    const float* as1 = (const float*)d_in[8];
    const float* ad1 = (const float*)d_in[9];
    const float* b1 = (const float*)d_in[10];
    const float* lw1 = (const float*)d_in[11];
    const float* lb1 = (const float*)d_in[12];
    const float* W2 = (const float*)d_in[13];
    const float* as2 = (const float*)d_in[14];
    const float* ad2 = (const float*)d_in[15];
    const float* b2 = (const float*)d_in[16];
    const float* lw2 = (const float*)d_in[17];
    const float* lb2 = (const float*)d_in[18];
    const float* W3 = (const float*)d_in[19];
    const float* as3 = (const float*)d_in[20];
    const float* ad3 = (const float*)d_in[21];
    const float* b3 = (const float*)d_in[22];
    const float* lw3 = (const float*)d_in[23];
    const float* lb3 = (const float*)d_in[24];

    const int n = in_sizes[0];       // 20000
    const int E = in_sizes[1] / 2;   // 320000
    const int N2 = 2 * n;

    float* MEAN = (float*)d_ws;                // [N2,128]
    float* LIN = MEAN + (size_t)N2 * 128;      // [N2,256]
    float* L3 = LIN + (size_t)N2 * 256;        // [N2,128]
    float* a_s = L3 + (size_t)N2 * 128;        // [N2,4]
    float* a_d = a_s + (size_t)N2 * 4;
    int* rp = (int*)(a_d + (size_t)N2 * 4);    // [N2]
    int* csr = rp + N2;                        // [2E]
    int* gs = csr + 2 * E;                     // [2G+1]
    unsigned char* X8a = (unsigned char*)(gs + 2 * GG + 4);  // [N2,256] fp8 (layers 1/2)
    unsigned char* X8b = X8a + (size_t)N2 * 256;             // [N2,512] fp8 (layer 3)
    __bf16* Abf = (__bf16*)(X8b + (size_t)N2 * 512);         // [N2,256] GEMM A
    __bf16* B1t = Abf + (size_t)N2 * 256;  // 528 x 128
    __bf16* B2t = B1t + 528 * 128;         // 528 x 256
    __bf16* B3t = B2t + 528 * 256;         // 656 x 256

    const int TB = 256;
    dim3 blk(TB);

    // weight prep (shared by both sides)
    k_wt<<<cdiv(128 * 256, TB), blk, 0, stream>>>(W1, B1t, 128, 256);
    k_wt<<<cdiv(128 * 256, TB), blk, 0, stream>>>(lw1, B1t + 256 * 128, 128, 256);
    k_wattn<<<cdiv(16 * 128, TB), blk, 0, stream>>>(W1, as1, ad1, B1t + 512 * 128, 128, 64);
    k_wt<<<cdiv(256 * 256, TB), blk, 0, stream>>>(W2, B2t, 256, 256);
    k_wt<<<cdiv(256 * 256, TB), blk, 0, stream>>>(lw2, B2t + 256 * 256, 256, 256);
    k_wattn<<<cdiv(16 * 256, TB), blk, 0, stream>>>(W2, as2, ad2, B2t + 512 * 256, 256, 64);
    k_wt<<<cdiv(256 * 512, TB), blk, 0, stream>>>(W3, B3t, 256, 512);
    k_wt<<<cdiv(256 * 128, TB), blk, 0, stream>>>(lw3, B3t + 512 * 256, 256, 128);
    k_wattn<<<cdiv(16 * 256, TB), blk, 0, stream>>>(W3, as3, ad3, B3t + 640 * 256, 256, 128);

    // combined CSR + graph bounds (once for all 3 layers, both sides)
    hipMemsetAsync(rp, 0, sizeof(int) * (size_t)N2, stream);
    k_hist2<<<cdiv(2 * E, TB), blk, 0, stream>>>(edge_l, edge_r, E, n, rp);
    k_scan<<<1, 1024, 0, stream>>>(rp, N2);
    k_fill2<<<cdiv(2 * E, TB), blk, 0, stream>>>(edge_l, edge_r, E, n, rp, csr);
    k_gbound2<<<cdiv(2 * GG + 1, 512), 512, 0, stream>>>(batch_l, batch_r, n, gs);

    // embed both sides -> Abf [N2,128]
    k_embed2<<<cdiv(N2 * 16, TB), blk, 0, stream>>>(x_l, x_r, emb, Abf, n, N2);

    // ---- layer 1 (K=128, Mx=256 -> fp8, Ml=256) ----
    k_gemm_all<128><<<dim3(cdiv(N2, 64), 2), blk, 0, stream>>>(
        Abf, B1t, N2, 256, 256, X8a, 256, LIN, 256, lb1, b1, a_s, a_d);
    k_agg12<<<cdiv(N2, 8), blk, 0, stream>>>(rp, csr, a_s, a_d, X8a, LIN, Abf, N2);

    // ---- layer 2 (K=256, Mx=256 -> fp8, Ml=256) ----
    k_gemm_all<256><<<dim3(cdiv(N2, 64), 2), blk, 0, stream>>>(
        Abf, B2t, N2, 256, 256, X8a, 256, LIN, 256, lb2, b2, a_s, a_d);
    k_agg12<<<cdiv(N2, 8), blk, 0, stream>>>(rp, csr, a_s, a_d, X8a, LIN, Abf, N2);

    // ---- layer 3 (K=256, Mx=512 -> fp8, Ml=128) ----
    k_gemm_all<256><<<dim3(cdiv(N2, 64), 2), blk, 0, stream>>>(
        Abf, B3t, N2, 512, 128, X8b, 512, L3, 128, lb3, nullptr, a_s, a_d);
    k_agg3<<<cdiv(N2, 8), blk, 0, stream>>>(rp, csr, a_s, a_d, (const unsigned int*)X8b, MEAN, N2);
    k_pool<<<2 * GG, 128, 0, stream>>>(MEAN, L3, b3, gs, (float*)d_out);
}

// Round 10
// 498.790 us; speedup vs baseline: 1.7474x; 1.1123x over previous
//
#include <hip/hip_runtime.h>

#define GG 256

typedef __bf16 bf16x8 __attribute__((ext_vector_type(8)));
typedef float floatx4 __attribute__((ext_vector_type(4)));
typedef float f32x2 __attribute__((ext_vector_type(2)));

__device__ __forceinline__ float lrelu(float x) { return x > 0.f ? x : 0.2f * x; }

// ---- fused weight prep: all transposes + attn projections in one kernel ----
__device__ __forceinline__ void wt1(const float* __restrict__ B, __bf16* __restrict__ Bt,
                                    int K, int M, int idx) {
    int k = idx / M, m = idx - k * M;
    Bt[(size_t)m * K + k] = (__bf16)B[idx];
}
__device__ __forceinline__ void wattn1(const float* __restrict__ W,
                                       const float* __restrict__ as_,
                                       const float* __restrict__ ad_,
                                       __bf16* __restrict__ dst, int K, int C, int idx) {
    int j = idx / K, k = idx - j * K;
    float v = 0.f;
    if (j < 8) {
        int h = j & 3;
        const float* att = (j < 4) ? as_ : ad_;
        int M = 4 * C;
        for (int c = 0; c < C; c++) v += W[(size_t)k * M + h * C + c] * att[h * C + c];
    }
    dst[(size_t)j * K + k] = (__bf16)v;
}

__global__ void k_wprep(const float* W1, const float* lw1, const float* as1, const float* ad1,
                        const float* W2, const float* lw2, const float* as2, const float* ad2,
                        const float* W3, const float* lw3, const float* as3, const float* ad3,
                        __bf16* B1t, __bf16* B2t, __bf16* B3t) {
    int idx = blockIdx.x * blockDim.x + threadIdx.x;
    if (idx < 32768) { wt1(W1, B1t, 128, 256, idx); return; }
    idx -= 32768;
    if (idx < 32768) { wt1(lw1, B1t + 256 * 128, 128, 256, idx); return; }
    idx -= 32768;
    if (idx < 2048) { wattn1(W1, as1, ad1, B1t + 512 * 128, 128, 64, idx); return; }
    idx -= 2048;
    if (idx < 65536) { wt1(W2, B2t, 256, 256, idx); return; }
    idx -= 65536;
    if (idx < 65536) { wt1(lw2, B2t + 256 * 256, 256, 256, idx); return; }
    idx -= 65536;
    if (idx < 4096) { wattn1(W2, as2, ad2, B2t + 512 * 256, 256, 64, idx); return; }
    idx -= 4096;
    if (idx < 131072) { wt1(W3, B3t, 256, 512, idx); return; }
    idx -= 131072;
    if (idx < 32768) { wt1(lw3, B3t + 512 * 256, 256, 128, idx); return; }
    idx -= 32768;
    if (idx < 4096) { wattn1(W3, as3, ad3, B3t + 640 * 256, 256, 128, idx); return; }
}

// All-in-one GEMM, register-pipelined staging: full-K A tile -> LDS -> A frags in
// regs; B tiles prefetched tile t+1 into REGISTERS while MFMA consumes tile t from
// the single LDS buffer. EMB: A comes from emb[x[i]] directly (layer 1).
// cols<Mx -> fp8 bytes into x8; [Mx,Mtot) -> lin fp32 +bias1(+bias2);
// mini-tile [Mtot,Mtot+16) -> a_s/a_d (blockIdx.y==1 only).
template <int K, bool EMB>
__global__ __launch_bounds__(256) void k_gemm_all(const __bf16* __restrict__ A,
                                                  const int* __restrict__ xl,
                                                  const int* __restrict__ xr,
                                                  const float* __restrict__ emb,
                                                  const __bf16* __restrict__ Bt,
                                                  int n, int n1, int Mx, int Ml,
                                                  unsigned char* __restrict__ x8, int ldx,
                                                  float* __restrict__ lin, int ldl,
                                                  const float* __restrict__ bias1,
                                                  const float* __restrict__ bias2,
                                                  float* __restrict__ a_s,
                                                  float* __restrict__ a_d) {
    constexpr int KS = K / 32;
    constexpr int LDK = K + 8;          // 16B-aligned rows, banks spread
    constexpr int LPR = K / 8;          // bf16x8 chunks per row
    constexpr int NCH = 64 * LPR / 256; // chunks per thread
    __shared__ __bf16 S[64 * LDK];
    int tid = threadIdx.x;
    int wave = tid >> 6, lane = tid & 63;
    int row0 = blockIdx.x * 64;
    // --- stage A (coalesced; optional fused embedding gather) ---
#pragma unroll
    for (int c = 0; c < NCH; c++) {
        int i = tid + c * 256;
        int r = i / LPR, ko = (i - r * LPR) * 8;
        int gr = row0 + r;
        bf16x8 v = {};
        if (gr < n) {
            if (EMB) {
                int xi = (gr < n1) ? xl[gr] : xr[gr - n1];
                const float4* src = (const float4*)(emb + ((size_t)xi << 7) + ko);
                float4 q0 = src[0], q1 = src[1];
                v = bf16x8{(__bf16)q0.x, (__bf16)q0.y, (__bf16)q0.z, (__bf16)q0.w,
                           (__bf16)q1.x, (__bf16)q1.y, (__bf16)q1.z, (__bf16)q1.w};
            } else {
                v = *(const bf16x8*)(A + (size_t)gr * K + ko);
            }
        }
        *(bf16x8*)&S[r * LDK + ko] = v;
    }
    __syncthreads();
    int kOff = (lane >> 4) * 8;
    int colBase = lane & 15;
    bf16x8 af[KS];
#pragma unroll
    for (int ks = 0; ks < KS; ks++)
        af[ks] = *(const bf16x8*)&S[(wave * 16 + colBase) * LDK + ks * 32 + kOff];
    int Mtot = Mx + Ml;
    int gr0 = row0 + wave * 16 + ((lane >> 4) << 2);
    int half = (Mtot / 128) * 64;
    int c0beg = blockIdx.y * half;
    int T = half / 64;
    bf16x8 regs[NCH];
    // prefetch tile 0
#pragma unroll
    for (int c = 0; c < NCH; c++) {
        int i = tid + c * 256;
        int r = i / LPR, ko = (i - r * LPR) * 8;
        regs[c] = *(const bf16x8*)(Bt + (size_t)(c0beg + r) * K + ko);
    }
    for (int t = 0; t < T; t++) {
        __syncthreads();  // prior reads of S (A hoist / prev MFMA) complete
#pragma unroll
        for (int c = 0; c < NCH; c++) {
            int i = tid + c * 256;
            int r = i / LPR, ko = (i - r * LPR) * 8;
            *(bf16x8*)&S[r * LDK + ko] = regs[c];
        }
        if (t + 1 < T) {  // prefetch next tile; latency hidden behind MFMA below
            int c0n = c0beg + (t + 1) * 64;
#pragma unroll
            for (int c = 0; c < NCH; c++) {
                int i = tid + c * 256;
                int r = i / LPR, ko = (i - r * LPR) * 8;
                regs[c] = *(const bf16x8*)(Bt + (size_t)(c0n + r) * K + ko);
            }
        }
        __syncthreads();  // this tile's LDS writes visible
        floatx4 acc[4] = {};
#pragma unroll
        for (int ct = 0; ct < 4; ct++) {
#pragma unroll
            for (int ks = 0; ks < KS; ks++) {
                bf16x8 bf = *(const bf16x8*)&S[(ct * 16 + colBase) * LDK + ks * 32 + kOff];
                acc[ct] = __builtin_amdgcn_mfma_f32_16x16x32_bf16(af[ks], bf, acc[ct], 0, 0, 0);
            }
        }
        int c0 = c0beg + t * 64;
        if (c0 < Mx) {  // fp8-byte feature output
#pragma unroll
            for (int r = 0; r < 4; r++) {
                int gr = gr0 + r;
                if (gr >= n) continue;
#pragma unroll
                for (int ct = 0; ct < 4; ct++) {
                    float v = acc[ct][r];
                    int p = __builtin_amdgcn_cvt_pk_fp8_f32(v, v, 0, false);
                    x8[(size_t)gr * ldx + c0 + ct * 16 + colBase] = (unsigned char)(p & 0xff);
                }
            }
        } else {
#pragma unroll
            for (int r = 0; r < 4; r++) {
                int gr = gr0 + r;
                if (gr >= n) continue;
#pragma unroll
                for (int ct = 0; ct < 4; ct++) {
                    int c2 = c0 + ct * 16 + colBase - Mx;
                    float v = acc[ct][r] + bias1[c2];
                    if (bias2) v += bias2[c2];
                    lin[(size_t)gr * ldl + c2] = v;
                }
            }
        }
    }
    if (blockIdx.y == 1) {  // attn mini-tile: 4 a_s + 4 a_d cols (L2-hot)
        floatx4 acc = {};
        const __bf16* bp = Bt + (size_t)(Mtot + colBase) * K + kOff;
#pragma unroll
        for (int ks = 0; ks < KS; ks++) {
            bf16x8 bf = *(const bf16x8*)(bp + ks * 32);
            acc = __builtin_amdgcn_mfma_f32_16x16x32_bf16(af[ks], bf, acc, 0, 0, 0);
        }
        if (colBase < 8) {
            float* dst = (colBase < 4) ? a_s : a_d;
            int h = colBase & 3;
#pragma unroll
            for (int r = 0; r < 4; r++) {
                int gr = gr0 + r;
                if (gr < n) dst[gr * 4 + h] = acc[r];
            }
        }
    }
}

// ---- combined-CSR build over both sides (side-1 ids offset by n) ----
__global__ void k_hist2(const int* __restrict__ el, const int* __restrict__ er,
                        int E, int n, int* __restrict__ deg) {
    int e = blockIdx.x * blockDim.x + threadIdx.x;
    if (e >= 2 * E) return;
    int d = (e < E) ? el[E + e] : er[E + (e - E)] + n;
    atomicAdd(&deg[d], 1);
}

__global__ __launch_bounds__(1024) void k_scan(int* __restrict__ rp, int n) {
    __shared__ int wsum[16];
    __shared__ int s_carry;
    int lane = threadIdx.x & 63, wid = threadIdx.x >> 6;
    if (threadIdx.x == 0) s_carry = 0;
    __syncthreads();
    for (int base = 0; base < n; base += 1024) {
        int i = base + threadIdx.x;
        int v = (i < n) ? rp[i] : 0;
        int inc = v;
#pragma unroll
        for (int off = 1; off < 64; off <<= 1) {
            int t = __shfl_up(inc, off, 64);
            if (lane >= off) inc += t;
        }
        if (lane == 63) wsum[wid] = inc;
        __syncthreads();
        int carry = s_carry;
        __syncthreads();
        if (wid == 0) {
            int wv = (lane < 16) ? wsum[lane] : 0;
            int winc = wv;
#pragma unroll
            for (int off = 1; off < 16; off <<= 1) {
                int t = __shfl_up(winc, off, 64);
                if (lane >= off) winc += t;
            }
            if (lane < 16) wsum[lane] = winc - wv;
            if (lane == 15) s_carry = carry + winc;
        }
        __syncthreads();
        if (i < n) rp[i] = carry + wsum[wid] + (inc - v);
        __syncthreads();
    }
}

__global__ void k_fill2(const int* __restrict__ el, const int* __restrict__ er,
                        int E, int n, int* __restrict__ rp, int* __restrict__ csr) {
    int e = blockIdx.x * blockDim.x + threadIdx.x;
    if (e >= 2 * E) return;
    int d, s;
    if (e < E) { s = el[e]; d = el[E + e]; }
    else       { s = er[e - E] + n; d = er[E + (e - E)] + n; }
    int pos = atomicAdd(&rp[d], 1);
    csr[pos] = s;
}

__device__ __forceinline__ void dec4(unsigned int u, float* f) {
    f32x2 a = __builtin_amdgcn_cvt_pk_f32_fp8(u, false);
    f32x2 b = __builtin_amdgcn_cvt_pk_f32_fp8(u, true);
    f[0] = a[0]; f[1] = a[1]; f[2] = b[0]; f[3] = b[1];
}

// Layers 1/2 aggregation on fp8 rows (256 B): 2 nodes/wave, broadcast csr reads,
// depth-2 (row, a_s) prefetch. out_bf = bf16(relu(agg/z + lin))
__global__ __launch_bounds__(256) void k_agg12(const int* __restrict__ rp,
                                               const int* __restrict__ csr,
                                               const float* __restrict__ a_s,
                                               const float* __restrict__ a_d,
                                               const unsigned char* __restrict__ x8,
                                               const float* __restrict__ lin,
                                               __bf16* __restrict__ out_bf, int n) {
    int wv = (int)((blockIdx.x * blockDim.x + threadIdx.x) >> 6);
    int lane = threadIdx.x & 63;
    int sub = lane >> 5, sl = lane & 31;
    int node = wv * 2 + sub;
    if (node >= n) return;
    int c0 = sl * 8;
    int h = sl >> 3;
    int start = node ? rp[node - 1] : 0;
    int end = rp[node];
    float ad = a_d[node * 4 + h];
    float z = __expf(lrelu(a_s[node * 4 + h] + ad));
    float acc[8];
    {
        uint2 u = *(const uint2*)(x8 + (size_t)node * 256 + c0);
        float f[8];
        dec4(u.x, f); dec4(u.y, f + 4);
#pragma unroll
        for (int j = 0; j < 8; j++) acc[j] = z * f[j];
    }
    uint2 u0 = {}, u1 = {};
    float A0 = 0.f, A1 = 0.f;
    if (start < end) {
        int s = csr[start];
        u0 = *(const uint2*)(x8 + (size_t)s * 256 + c0);
        A0 = a_s[s * 4 + h];
    }
    if (start + 1 < end) {
        int s = csr[start + 1];
        u1 = *(const uint2*)(x8 + (size_t)s * 256 + c0);
        A1 = a_s[s * 4 + h];
    }
    for (int e = start; e < end; e++) {
        uint2 uc = u0;
        float ac = A0;
        u0 = u1; A0 = A1;
        if (e + 2 < end) {
            int s = csr[e + 2];
            u1 = *(const uint2*)(x8 + (size_t)s * 256 + c0);
            A1 = a_s[s * 4 + h];
        }
        float w = __expf(lrelu(ac + ad));
        z += w;
        float f[8];
        dec4(uc.x, f); dec4(uc.y, f + 4);
#pragma unroll
        for (int q = 0; q < 8; q++) acc[q] += w * f[q];
    }
    float inv = 1.f / (z + 1e-16f);
    const float4* lp = (const float4*)(lin + (size_t)node * 256 + c0);
    float4 l0 = lp[0], l1 = lp[1];
    float lf[8] = {l0.x, l0.y, l0.z, l0.w, l1.x, l1.y, l1.z, l1.w};
    bf16x8 r;
#pragma unroll
    for (int j = 0; j < 8; j++)
        r[j] = (__bf16)fmaxf(acc[j] * inv + lf[j], 0.f);
    *(bf16x8*)(out_bf + (size_t)node * 256 + c0) = r;
}

// Layer-3 aggregation (HC=512) on fp8 rows; depth-2 prefetch; head-mean -> mean[n,128]
__global__ __launch_bounds__(256) void k_agg3(const int* __restrict__ rp,
                                              const int* __restrict__ csr,
                                              const float* __restrict__ a_s,
                                              const float* __restrict__ a_d,
                                              const unsigned int* __restrict__ x8,
                                              float* __restrict__ mean, int n) {
    int wv = (int)((blockIdx.x * blockDim.x + threadIdx.x) >> 6);
    int lane = threadIdx.x & 63;
    int sub = lane >> 5, sl = lane & 31;
    int node = wv * 2 + sub;
    if (node >= n) return;
    int h = sl >> 3;
    int start = node ? rp[node - 1] : 0;
    int end = rp[node];
    float ad = a_d[node * 4 + h];
    float z = __expf(lrelu(a_s[node * 4 + h] + ad));
    float acc[16];
    {
        uint4 u = *(const uint4*)(x8 + (size_t)node * 128 + sl * 4);
        float f[16];
        dec4(u.x, f); dec4(u.y, f + 4); dec4(u.z, f + 8); dec4(u.w, f + 12);
#pragma unroll
        for (int j = 0; j < 16; j++) acc[j] = z * f[j];
    }
    uint4 u0 = {}, u1 = {};
    float A0 = 0.f, A1 = 0.f;
    if (start < end) {
        int s = csr[start];
        u0 = *(const uint4*)(x8 + (size_t)s * 128 + sl * 4);
        A0 = a_s[s * 4 + h];
    }
    if (start + 1 < end) {
        int s = csr[start + 1];
        u1 = *(const uint4*)(x8 + (size_t)s * 128 + sl * 4);
        A1 = a_s[s * 4 + h];
    }
    for (int e = start; e < end; e++) {
        uint4 uc = u0;
        float ac = A0;
        u0 = u1; A0 = A1;
        if (e + 2 < end) {
            int s = csr[e + 2];
            u1 = *(const uint4*)(x8 + (size_t)s * 128 + sl * 4);
            A1 = a_s[s * 4 + h];
        }
        float w = __expf(lrelu(ac + ad));
        z += w;
        float f[16];
        dec4(uc.x, f); dec4(uc.y, f + 4); dec4(uc.z, f + 8); dec4(uc.w, f + 12);
#pragma unroll
        for (int q = 0; q < 16; q++) acc[q] += w * f[q];
    }
    float scale = 0.25f / (z + 1e-16f);
#pragma unroll
    for (int j = 0; j < 16; j++) {
        float v = acc[j] * scale;
        v += __shfl_xor(v, 8, 64);
        v += __shfl_xor(v, 16, 64);
        acc[j] = v;
    }
    if ((sl & 24) == 0) {
        float4* op = (float4*)(mean + (size_t)node * 128 + sl * 16);
#pragma unroll
        for (int q = 0; q < 4; q++) {
            float4 o = {acc[4 * q], acc[4 * q + 1], acc[4 * q + 2], acc[4 * q + 3]};
            op[q] = o;
        }
    }
}

// per-graph mean pool (2G blocks), inline binary search on sorted batch
__global__ __launch_bounds__(128) void k_pool(const float* __restrict__ mean,
                                              const float* __restrict__ lin3,
                                              const float* __restrict__ b3,
                                              const int* __restrict__ bl,
                                              const int* __restrict__ br,
                                              int n, float* __restrict__ out) {
    int g = blockIdx.x, c = threadIdx.x;
    const int* b = (g < GG) ? bl : br;
    int tg = (g < GG) ? g : g - GG;
    int off = (g < GG) ? 0 : n;
    int s, e;
    { int lo = 0, hi = n; while (lo < hi) { int m = (lo + hi) >> 1; if (b[m] < tg) lo = m + 1; else hi = m; } s = lo; }
    { int lo = 0, hi = n; while (lo < hi) { int m = (lo + hi) >> 1; if (b[m] < tg + 1) lo = m + 1; else hi = m; } e = lo; }
    s += off; e += off;
    float acc = 0.f;
    for (int i = s; i < e; i++)
        acc += mean[(size_t)i * 128 + c] + lin3[(size_t)i * 128 + c];
    int cnt = e - s;
    out[(size_t)g * 128 + c] = cnt > 0 ? acc / (float)cnt + b3[c] : 0.f;
}

static inline int cdiv(int a, int b) { return (a + b - 1) / b; }

extern "C" void kernel_launch(void* const* d_in, const int* in_sizes, int n_in,
                              void* d_out, int out_size, void* d_ws, size_t ws_size,
                              hipStream_t stream) {
    const int* x_l = (const int*)d_in[0];
    const int* edge_l = (const int*)d_in[1];
    const int* batch_l = (const int*)d_in[2];
    const int* x_r = (const int*)d_in[3];
    const int* edge_r = (const int*)d_in[4];
    const int* batch_r = (const int*)d_in[5];
    const float* emb = (const float*)d_in[6];
    const float* W1 = (const float*)d_in[7];
    const float* as1 = (const float*)d_in[8];
    const float* ad1 = (const float*)d_in[9];
    const float* b1 = (const float*)d_in[10];
    const float* lw1 = (const float*)d_in[11];
    const float* lb1 = (const float*)d_in[12];
    const float* W2 = (const float*)d_in[13];
    const float* as2 = (const float*)d_in[14];
    const float* ad2 = (const float*)d_in[15];
    const float* b2 = (const float*)d_in[16];
    const float* lw2 = (const float*)d_in[17];
    const float* lb2 = (const float*)d_in[18];
    const float* W3 = (const float*)d_in[19];
    const float* as3 = (const float*)d_in[20];
    const float* ad3 = (const float*)d_in[21];
    const float* b3 = (const float*)d_in[22];
    const float* lw3 = (const float*)d_in[23];
    const float* lb3 = (const float*)d_in[24];

    const int n = in_sizes[0];       // 20000
    const int E = in_sizes[1] / 2;   // 320000
    const int N2 = 2 * n;

    float* MEAN = (float*)d_ws;                // [N2,128]
    float* LIN = MEAN + (size_t)N2 * 128;      // [N2,256]
    float* L3 = LIN + (size_t)N2 * 256;        // [N2,128]
    float* a_s = L3 + (size_t)N2 * 128;        // [N2,4]
    float* a_d = a_s + (size_t)N2 * 4;
    int* rp = (int*)(a_d + (size_t)N2 * 4);    // [N2]
    int* csr = rp + N2;                        // [2E]
    unsigned char* X8a = (unsigned char*)(csr + 2 * E);  // [N2,256] fp8 (layers 1/2)
    unsigned char* X8b = X8a + (size_t)N2 * 256;         // [N2,512] fp8 (layer 3)
    __bf16* Abf = (__bf16*)(X8b + (size_t)N2 * 512);     // [N2,256] GEMM A (layers 2/3)
    __bf16* B1t = Abf + (size_t)N2 * 256;  // 528 x 128
    __bf16* B2t = B1t + 528 * 128;         // 528 x 256
    __bf16* B3t = B2t + 528 * 256;         // 656 x 256

    const int TB = 256;
    dim3 blk(TB);

    // fused weight prep (1 dispatch)
    k_wprep<<<cdiv(370688, TB), blk, 0, stream>>>(W1, lw1, as1, ad1, W2, lw2, as2, ad2,
                                                  W3, lw3, as3, ad3, B1t, B2t, B3t);

    // combined CSR (once for all 3 layers, both sides)
    hipMemsetAsync(rp, 0, sizeof(int) * (size_t)N2, stream);
    k_hist2<<<cdiv(2 * E, TB), blk, 0, stream>>>(edge_l, edge_r, E, n, rp);
    k_scan<<<1, 1024, 0, stream>>>(rp, N2);
    k_fill2<<<cdiv(2 * E, TB), blk, 0, stream>>>(edge_l, edge_r, E, n, rp, csr);

    // ---- layer 1 (K=128, embed fused into A staging, Mx=256 -> fp8, Ml=256) ----
    k_gemm_all<128, true><<<dim3(cdiv(N2, 64), 2), blk, 0, stream>>>(
        nullptr, x_l, x_r, emb, B1t, N2, n, 256, 256, X8a, 256, LIN, 256, lb1, b1, a_s, a_d);
    k_agg12<<<cdiv(N2, 8), blk, 0, stream>>>(rp, csr, a_s, a_d, X8a, LIN, Abf, N2);

    // ---- layer 2 (K=256, Mx=256 -> fp8, Ml=256) ----
    k_gemm_all<256, false><<<dim3(cdiv(N2, 64), 2), blk, 0, stream>>>(
        Abf, nullptr, nullptr, nullptr, B2t, N2, n, 256, 256, X8a, 256, LIN, 256, lb2, b2, a_s, a_d);
    k_agg12<<<cdiv(N2, 8), blk, 0, stream>>>(rp, csr, a_s, a_d, X8a, LIN, Abf, N2);

    // ---- layer 3 (K=256, Mx=512 -> fp8, Ml=128) ----
    k_gemm_all<256, false><<<dim3(cdiv(N2, 64), 2), blk, 0, stream>>>(
        Abf, nullptr, nullptr, nullptr, B3t, N2, n, 512, 128, X8b, 512, L3, 128, lb3, nullptr, a_s, a_d);
    k_agg3<<<cdiv(N2, 8), blk, 0, stream>>>(rp, csr, a_s, a_d, (const unsigned int*)X8b, MEAN, N2);
    k_pool<<<2 * GG, 128, 0, stream>>>(MEAN, L3, b3, batch_l, batch_r, n, (float*)d_out);
}